// Round 8
// baseline (317.302 us; speedup 1.0000x reference)
//
#include <hip/hip_runtime.h>
#include <hip/hip_bf16.h>

typedef __attribute__((ext_vector_type(8))) __bf16 bf16x8;
typedef __attribute__((ext_vector_type(4))) float f32x4;
typedef unsigned short ushort_t;
typedef unsigned int uint_t;
typedef __attribute__((ext_vector_type(4))) uint_t uint4v;

#define CCH 256
#define BB 4

// kc-plane strides in shorts: level npix * 32 ch
#define NP32_0 3145728   // 4*128*192*32
#define NP32_1 786432    // 4*64*96*32
#define NP32_2 196608    // 4*32*48*32
#define NP32_3 49152     // 4*16*24*32

__device__ __forceinline__ ushort_t f2b(float v) {
    __hip_bfloat16 h = __float2bfloat16(v);
    return *reinterpret_cast<ushort_t*>(&h);
}

__device__ __forceinline__ void gload16(const void* g, void* l) {
    __builtin_amdgcn_global_load_lds(
        (const __attribute__((address_space(1))) void*)g,
        (__attribute__((address_space(3))) void*)l, 16, 0, 0);
}

// nontemporal 16B store (evict-first; streaming bf16 outputs)
__device__ __forceinline__ void nts(ushort_t* p, uint_t a, uint_t b, uint_t c, uint_t d) {
    uint4v v = {a, b, c, d};
    __builtin_nontemporal_store(v, reinterpret_cast<uint4v*>(p));
}

struct PrepPtrs {
    ushort_t* o0; ushort_t* o1; ushort_t* o2; ushort_t* o3;
    float* n0; float* n1; float* n2; float* n3;
};

// =====================================================================
// pyr_prep v5: v4 structure, but all bf16 output stores are
// NONTEMPORAL (test of the L2-thrash write-amplification theory:
// logical writes 134MB, measured 321MB with normal stores).
// =====================================================================
__global__ __launch_bounds__(256, 3) void pyr_prep_kernel(
    const float* __restrict__ fa, const float* __restrict__ fb,
    PrepPtrs Pa, PrepPtrs Pb)
{
    const int H = 128, W = 192;
    const int HW = H * W;
    const float* fin = blockIdx.y ? fb : fa;
    PrepPtrs P = blockIdx.y ? Pb : Pa;

    __shared__ float lds0[32 * 260];   // [c:32][p:256 pad->260]
    __shared__ float lds1[32 * 68];    // [c:32][q:64 pad->68]
    __shared__ float lds2[32 * 20];    // [c:32][s:16 pad->20]
    __shared__ float lds3[32 * 8];     // [c:32][u:4 pad->8]
    __shared__ float red[256];

    int xc = blockIdx.x % 6;
    int ys = (blockIdx.x / 6) % 16;
    int b  = blockIdx.x / 96;
    int gx0 = xc * 32, gy0 = ys * 8;
    int t = threadIdx.x;

    const float* gsrc[8];
    int lofs[8];
    #pragma unroll
    for (int j = 0; j < 8; ++j) {
        int e = t + 256 * j;
        int c = e >> 6, r = (e >> 3) & 7, x4 = e & 7;
        gsrc[j] = fin + ((size_t)(b * 256 + c) * H + gy0 + r) * W + gx0 + 4 * x4;
        lofs[j] = c * 260 + r * 32 + 4 * x4;
    }

    float4 stg[8];
    auto issue = [&](int kc) {
        #pragma unroll
        for (int j = 0; j < 8; ++j)
            stg[j] = *reinterpret_cast<const float4*>(gsrc[j] + (size_t)kc * (32 * HW));
    };

    float ssq0 = 0.f, ssq1 = 0.f, ssq2 = 0.f, ssq3 = 0.f;

    size_t p0g = (size_t)(b * H + gy0 + (t >> 5)) * W + gx0 + (t & 31);     // L0 pixel
    int wv = t >> 6, q = t & 63, qy = q >> 4, qx = q & 15;                  // L1 compute
    int cb2 = t >> 4, sI = t & 15, sy2 = sI >> 3, sx2 = sI & 7;             // L2 compute (t<128)
    int cb3 = t >> 2, u3 = t & 3;                                           // L3 compute (t<32)
    size_t l1s = (size_t)(b * 64 + ys * 4 + (t >> 4)) * 96 + xc * 16 + (t & 15);   // t<64
    size_t l2s = (size_t)(b * 32 + ys * 2 + (t >> 3)) * 48 + xc * 8 + (t & 7);     // t<16
    size_t l3s = (size_t)(b * 16 + ys) * 24 + xc * 4 + t;                          // t<4

    issue(0);
    #pragma unroll 1
    for (int kc = 0; kc < 8; ++kc) {
        // ---- A: regs -> lds0 (b128, conflict-free) ----
        #pragma unroll
        for (int j = 0; j < 8; ++j)
            *reinterpret_cast<float4*>(&lds0[lofs[j]]) = stg[j];
        if (kc < 7) issue(kc + 1);
        __syncthreads();

        // ---- region 1: L0 store (nt, 64B/lane) + L1 pool compute ----
        {
            uint_t uu[16];
            #pragma unroll
            for (int i = 0; i < 16; ++i) {
                float va = lds0[(2 * i) * 260 + t];
                float vb = lds0[(2 * i + 1) * 260 + t];
                ssq0 = fmaf(va, va, ssq0);
                ssq0 = fmaf(vb, vb, ssq0);
                uu[i] = (uint_t)f2b(va) | ((uint_t)f2b(vb) << 16);
            }
            ushort_t* dst = P.o0 + (size_t)kc * NP32_0 + p0g * 32;
            nts(dst +  0, uu[0],  uu[1],  uu[2],  uu[3]);
            nts(dst +  8, uu[4],  uu[5],  uu[6],  uu[7]);
            nts(dst + 16, uu[8],  uu[9],  uu[10], uu[11]);
            nts(dst + 24, uu[12], uu[13], uu[14], uu[15]);
        }
        {
            #pragma unroll
            for (int h = 0; h < 8; ++h) {
                int c = wv * 8 + h;
                float2 s0 = *reinterpret_cast<const float2*>(&lds0[c * 260 + (2 * qy) * 32 + 2 * qx]);
                float2 s1 = *reinterpret_cast<const float2*>(&lds0[c * 260 + (2 * qy + 1) * 32 + 2 * qx]);
                float a = 0.25f * (s0.x + s0.y + s1.x + s1.y);
                ssq1 = fmaf(a, a, ssq1);
                lds1[c * 68 + q] = a;
            }
        }
        __syncthreads();

        // ---- region 2: L1 store (t<64, nt 64B) + L2 pool compute (t<128) ----
        if (t < 64) {
            uint_t uu[16];
            #pragma unroll
            for (int i = 0; i < 16; ++i) {
                float va = lds1[(2 * i) * 68 + t];
                float vb = lds1[(2 * i + 1) * 68 + t];
                uu[i] = (uint_t)f2b(va) | ((uint_t)f2b(vb) << 16);
            }
            ushort_t* dst = P.o1 + (size_t)kc * NP32_1 + l1s * 32;
            nts(dst +  0, uu[0],  uu[1],  uu[2],  uu[3]);
            nts(dst +  8, uu[4],  uu[5],  uu[6],  uu[7]);
            nts(dst + 16, uu[8],  uu[9],  uu[10], uu[11]);
            nts(dst + 24, uu[12], uu[13], uu[14], uu[15]);
        }
        if (t < 128) {
            #pragma unroll
            for (int cc = 0; cc < 4; ++cc) {
                int c = cb2 * 4 + cc;
                float2 s0 = *reinterpret_cast<const float2*>(&lds1[c * 68 + (2 * sy2) * 16 + 2 * sx2]);
                float2 s1 = *reinterpret_cast<const float2*>(&lds1[c * 68 + (2 * sy2 + 1) * 16 + 2 * sx2]);
                float a = 0.25f * (s0.x + s0.y + s1.x + s1.y);
                ssq2 = fmaf(a, a, ssq2);
                lds2[c * 20 + sI] = a;
            }
        }
        __syncthreads();

        // ---- region 3: L2 store (t<16, nt 64B) + L3 pool compute (t<32) ----
        if (t < 16) {
            uint_t uu[16];
            #pragma unroll
            for (int i = 0; i < 16; ++i) {
                float va = lds2[(2 * i) * 20 + t];
                float vb = lds2[(2 * i + 1) * 20 + t];
                uu[i] = (uint_t)f2b(va) | ((uint_t)f2b(vb) << 16);
            }
            ushort_t* dst = P.o2 + (size_t)kc * NP32_2 + l2s * 32;
            nts(dst +  0, uu[0],  uu[1],  uu[2],  uu[3]);
            nts(dst +  8, uu[4],  uu[5],  uu[6],  uu[7]);
            nts(dst + 16, uu[8],  uu[9],  uu[10], uu[11]);
            nts(dst + 24, uu[12], uu[13], uu[14], uu[15]);
        }
        if (t < 32) {
            #pragma unroll
            for (int cc = 0; cc < 4; ++cc) {
                int c = cb3 * 4 + cc;
                float2 s0 = *reinterpret_cast<const float2*>(&lds2[c * 20 + 2 * u3]);
                float2 s1 = *reinterpret_cast<const float2*>(&lds2[c * 20 + 8 + 2 * u3]);
                float a = 0.25f * (s0.x + s0.y + s1.x + s1.y);
                ssq3 = fmaf(a, a, ssq3);
                lds3[c * 8 + u3] = a;
            }
        }
        __syncthreads();

        // ---- region 4: L3 store (t<4, nt 64B) ----
        if (t < 4) {
            uint_t uu[16];
            #pragma unroll
            for (int i = 0; i < 16; ++i) {
                float va = lds3[(2 * i) * 8 + t];
                float vb = lds3[(2 * i + 1) * 8 + t];
                uu[i] = (uint_t)f2b(va) | ((uint_t)f2b(vb) << 16);
            }
            ushort_t* dst = P.o3 + (size_t)kc * NP32_3 + l3s * 32;
            nts(dst +  0, uu[0],  uu[1],  uu[2],  uu[3]);
            nts(dst +  8, uu[4],  uu[5],  uu[6],  uu[7]);
            nts(dst + 16, uu[8],  uu[9],  uu[10], uu[11]);
            nts(dst + 24, uu[12], uu[13], uu[14], uu[15]);
        }
    }

    // ---- invnorm reductions ----
    P.n0[p0g] = 1.f / fmaxf(sqrtf(ssq0), 1e-12f);
    red[t] = ssq1;
    __syncthreads();
    if (t < 64) {
        float sm = red[t] + red[t + 64] + red[t + 128] + red[t + 192];
        P.n1[l1s] = 1.f / fmaxf(sqrtf(sm), 1e-12f);
    }
    __syncthreads();
    if (t < 128) red[t] = ssq2;
    __syncthreads();
    if (t < 16) {
        float sm = 0.f;
        #pragma unroll
        for (int c = 0; c < 8; ++c) sm += red[t + 16 * c];
        P.n2[l2s] = 1.f / fmaxf(sqrtf(sm), 1e-12f);
    }
    __syncthreads();
    if (t < 32) red[t] = ssq3;
    __syncthreads();
    if (t < 4) {
        float sm = 0.f;
        #pragma unroll
        for (int c = 0; c < 8; ++c) sm += red[t + 4 * c];
        P.n3[l3s] = 1.f / fmaxf(sqrtf(sm), 1e-12f);
    }
}

// =====================================================================
// corr_mfma2 v2: counted vmcnt(8) pipeline (T4). Next-chunk loads stay
// in flight across the barrier; 2 barriers/chunk, no full drain.
// =====================================================================
__global__ __launch_bounds__(256, 2) void corr_mfma2_kernel(
    const ushort_t* __restrict__ f1n, const ushort_t* __restrict__ f2n,
    const float* __restrict__ invn1, const float* __restrict__ invn2,
    const float* __restrict__ dt, float* __restrict__ out,
    const ushort_t* __restrict__ zblk, int H, int W, int TX, int TY, int npix32)
{
    __shared__ char smem[65536];
    char* As = smem;
    char* Bs = smem + 16384;

    int bid = blockIdx.x;
    int cpx = gridDim.x >> 3;
    int swz = (bid & 7) * cpx + (bid >> 3);
    int tx = swz % TX;
    int ty = (swz / TX) % TY;
    int b  = swz / (TX * TY);
    int x0 = tx * 16, y0 = ty * 8;

    int tid = threadIdx.x;
    int w = tid >> 6, lane = tid & 63;
    int kg = lane >> 4, col = lane & 15;
    int r2 = col >> 2, c2 = col & 3;
    int sy = w >> 1, p = w & 1;

    const ushort_t* srcA[2]; char* ldsA[2];
    #pragma unroll
    for (int q = 0; q < 2; ++q) {
        int qq = w * 2 + q;
        int kgs = qq >> 1, reg = qq & 1;
        int slot = reg * 64 + lane;
        int ly = slot >> 4, lxp = slot & 15;
        int lx = lxp ^ (4 * (ly & 1));
        srcA[q] = f1n + ((size_t)((b * H + y0 + ly) * W) + x0 + lx) * 32 + kgs * 8;
        ldsA[q] = As + qq * 1024;
    }
    const ushort_t* srcB[6]; int advB[6]; char* ldsB[6];
    #pragma unroll
    for (int q = 0; q < 6; ++q) {
        int qq = w * 6 + q;
        int kgs = qq / 6, reg = qq % 6;
        int slot = reg * 64 + lane;
        int wy = slot / 24, wxp = slot % 24;
        int wx = wxp ^ (4 * (wy & 1));
        int py = y0 - 4 + wy, px = x0 - 4 + wx;
        bool v = (py >= 0) && (py < H) && (px >= 0) && (px < W);
        srcB[q] = v ? (f2n + ((size_t)((b * H + py) * W) + px) * 32 + kgs * 8) : zblk;
        advB[q] = v ? npix32 : 0;
        ldsB[q] = Bs + qq * 1024;
    }

    int aoff[2], boff[3][4];
    #pragma unroll
    for (int s = 0; s < 2; ++s) {
        int sxs = 2 * p + s;
        int ly = 4 * sy + r2;
        int lx = (4 * sxs + c2) ^ (4 * (ly & 1));
        aoff[s] = kg * 2048 + (ly * 16 + lx) * 16;
    }
    #pragma unroll
    for (int i = 0; i < 3; ++i)
        #pragma unroll
        for (int j = 0; j < 4; ++j) {
            int wy = 4 * (sy + i) + r2;
            int wx = (4 * (2 * p + j) + c2) ^ (4 * (wy & 1));
            boff[i][j] = kg * 6144 + (wy * 24 + wx) * 16;
        }

    f32x4 acc0[3][3] = {};
    f32x4 acc1[3][3] = {};

    // prologue: issue chunk 0 into buf 0 (no wait here — kc=0's vmcnt covers it)
    #pragma unroll
    for (int q = 0; q < 2; ++q) { gload16(srcA[q], ldsA[q]); srcA[q] += npix32; }
    #pragma unroll
    for (int q = 0; q < 6; ++q) { gload16(srcB[q], ldsB[q]); srcB[q] += advB[q]; }

    int buf = 0;
    #pragma unroll 1
    for (int kc = 0; kc < 8; ++kc) {
        if (kc < 7) {
            int boA = (buf ^ 1) * 8192;
            int boB = (buf ^ 1) * 24576;
            #pragma unroll
            for (int q = 0; q < 2; ++q) { gload16(srcA[q], ldsA[q] + boA); srcA[q] += npix32; }
            #pragma unroll
            for (int q = 0; q < 6; ++q) { gload16(srcB[q], ldsB[q] + boB); srcB[q] += advB[q]; }
            __builtin_amdgcn_sched_barrier(0);
            asm volatile("s_waitcnt vmcnt(8)" ::: "memory");   // cur buf's 8 landed; next 8 in flight
        } else {
            __builtin_amdgcn_sched_barrier(0);
            asm volatile("s_waitcnt vmcnt(0)" ::: "memory");
        }
        __builtin_amdgcn_s_barrier();          // barrier 1: cur buf ready for all waves
        __builtin_amdgcn_sched_barrier(0);

        const char* Ab = As + buf * 8192;
        const char* Bb = Bs + buf * 24576;
        bf16x8 av0 = *(const bf16x8*)(Ab + aoff[0]);
        bf16x8 av1 = *(const bf16x8*)(Ab + aoff[1]);
        #pragma unroll
        for (int i = 0; i < 3; ++i) {
            #pragma unroll
            for (int j = 0; j < 4; ++j) {
                bf16x8 bv = *(const bf16x8*)(Bb + boff[i][j]);
                if (j < 3) acc0[i][j]     = __builtin_amdgcn_mfma_f32_16x16x32_bf16(av0, bv, acc0[i][j], 0, 0, 0);
                if (j > 0) acc1[i][j - 1] = __builtin_amdgcn_mfma_f32_16x16x32_bf16(av1, bv, acc1[i][j - 1], 0, 0, 0);
            }
        }
        if (kc < 7) {
            __builtin_amdgcn_sched_barrier(0);
            __builtin_amdgcn_s_barrier();      // barrier 2: all done reading buf before next overwrite
            __builtin_amdgcn_sched_barrier(0);
        }
        buf ^= 1;
    }

    float inv1v[2][4], dtv[2][4];
    #pragma unroll
    for (int s = 0; s < 2; ++s) {
        int sxs = 2 * p + s;
        #pragma unroll
        for (int rr = 0; rr < 4; ++rr) {
            int m = kg * 4 + rr;
            int iy = m >> 2, ix = m & 3;
            int pix = (b * H + y0 + 4 * sy + iy) * W + x0 + 4 * sxs + ix;
            inv1v[s][rr] = invn1[pix];
            dtv[s][rr]   = dt[pix];
        }
    }
    #pragma unroll
    for (int s = 0; s < 2; ++s) {
        int sxs = 2 * p + s;
        #pragma unroll
        for (int i = 0; i < 3; ++i) {
            #pragma unroll
            for (int jj = 0; jj < 3; ++jj) {
                int wy = 4 * (sy + i) + r2;
                int wxr = 4 * (sxs + jj) + c2;
                int py = y0 - 4 + wy, px = x0 - 4 + wxr;
                bool v = (py >= 0) && (py < H) && (px >= 0) && (px < W);
                float i2 = v ? invn2[(b * H + py) * W + px] : 0.f;
                f32x4 a = (s == 0) ? acc0[i][jj] : acc1[i][jj];
                #pragma unroll
                for (int rr = 0; rr < 4; ++rr) {
                    int m = kg * 4 + rr;
                    int iy = m >> 2, ix = m & 3;
                    int oy = iy + 8 - (4 * i + r2);
                    int ox = ix + 8 - (4 * jj + c2);
                    if (oy >= 0 && oy < 9 && ox >= 0 && ox < 9) {
                        int gy = y0 + 4 * sy + iy, gx = x0 + 4 * sxs + ix;
                        out[((size_t)(b * 81 + oy * 9 + ox) * H + gy) * W + gx]
                            = a[rr] * inv1v[s][rr] * i2 + dtv[s][rr];
                    }
                }
            }
        }
    }
}

// =====================================================================
// corr_mfma — L3 only, kc-blocked layout
// =====================================================================
__global__ __launch_bounds__(256) void corr_mfma_kernel(
    const ushort_t* __restrict__ f1n, const ushort_t* __restrict__ f2n,
    const float* __restrict__ invn1, const float* __restrict__ invn2,
    const float* __restrict__ dt, float* __restrict__ out,
    int H, int W, int TX, int TY, int zoff)
{
    int wid  = threadIdx.x >> 6;
    int lane = threadIdx.x & 63;
    int tile = blockIdx.x * 4 + wid;
    int ntiles = BB * TY * TX;
    if (tile >= ntiles) return;
    int tx = tile % TX;
    int ty = (tile / TX) % TY;
    int b  = tile / (TX * TY);
    int x0 = tx * 4, y0 = ty * 4;

    int col = lane & 15;
    int kg  = lane >> 4;

    int iyA = col >> 2, ixA = col & 3;
    int a_off = (((b * H + y0 + iyA) * W) + x0 + ixA) * 32 + kg * 8;

    int b_off[9], badv[9];
    uint_t vmask = 0;
    #pragma unroll
    for (int tt = 0; tt < 9; ++tt) {
        int w = tt * 16 + col;
        int wy = w / 12, wx = w % 12;
        int py = y0 + wy - 4, px = x0 + wx - 4;
        bool v = (py >= 0) && (py < H) && (px >= 0) && (px < W);
        b_off[tt] = v ? (((b * H + py) * W + px) * 32 + kg * 8) : (zoff + kg * 8);
        badv[tt] = v ? NP32_3 : 0;
        if (v) vmask |= (1u << tt);
    }

    f32x4 acc[9] = {};
    #pragma unroll
    for (int kb = 0; kb < 8; ++kb) {
        bf16x8 av = *reinterpret_cast<const bf16x8*>(f1n + a_off + kb * NP32_3);
        #pragma unroll
        for (int tt = 0; tt < 9; ++tt) {
            bf16x8 bv = *reinterpret_cast<const bf16x8*>(f2n + b_off[tt]);
            acc[tt] = __builtin_amdgcn_mfma_f32_16x16x32_bf16(av, bv, acc[tt], 0, 0, 0);
            b_off[tt] += badv[tt];
        }
    }

    float inv1[4], dts[4];
    #pragma unroll
    for (int r = 0; r < 4; ++r) {
        int m = kg * 4 + r;
        int iy = m >> 2, ix = m & 3;
        int pix = (b * H + y0 + iy) * W + x0 + ix;
        inv1[r] = invn1[pix];
        dts[r]  = dt[pix];
    }
    #pragma unroll
    for (int tt = 0; tt < 9; ++tt) {
        int w = tt * 16 + col;
        int wy = w / 12, wx = w % 12;
        int py = y0 + wy - 4, px = x0 + wx - 4;
        float i2 = ((vmask >> tt) & 1u) ? invn2[(b * H + py) * W + px] : 0.f;
        #pragma unroll
        for (int r = 0; r < 4; ++r) {
            int m = kg * 4 + r;
            int iy = m >> 2, ix = m & 3;
            int oy = iy + 8 - wy, ox = ix + 8 - wx;
            if (oy >= 0 && oy < 9 && ox >= 0 && ox < 9) {
                int o = oy * 9 + ox;
                out[((size_t)(b * 81 + o) * H + (y0 + iy)) * W + (x0 + ix)]
                    = acc[tt][r] * inv1[r] * i2 + dts[r];
            }
        }
    }
}

// =====================================================================
// depth: one thread owns an 8x8 L0 patch; dt for all 4 levels
// =====================================================================
__global__ __launch_bounds__(256) void depth_kernel(
    const float* __restrict__ d1, const float* __restrict__ d2,
    const float* __restrict__ dw,
    float* __restrict__ dt0, float* __restrict__ dt1,
    float* __restrict__ dt2, float* __restrict__ dt3)
{
    int rid = blockIdx.x * 256 + threadIdx.x;
    if (rid >= 4 * 16 * 24) return;
    int b = rid / 384, rr = rid % 384, ry = rr / 24, rx = rr % 24;
    const int H = 128, W = 192;
    float w0 = dw[0];
    size_t base0 = ((size_t)b * H + ry * 8) * W + rx * 8;

    float q1[4][4], q2[4][4];
    #pragma unroll
    for (int yy = 0; yy < 4; ++yy) {
        float4 a0 = *reinterpret_cast<const float4*>(d1 + base0 + (2 * yy) * W);
        float4 a1 = *reinterpret_cast<const float4*>(d1 + base0 + (2 * yy) * W + 4);
        float4 a2 = *reinterpret_cast<const float4*>(d1 + base0 + (2 * yy + 1) * W);
        float4 a3 = *reinterpret_cast<const float4*>(d1 + base0 + (2 * yy + 1) * W + 4);
        float4 b0 = *reinterpret_cast<const float4*>(d2 + base0 + (2 * yy) * W);
        float4 b1 = *reinterpret_cast<const float4*>(d2 + base0 + (2 * yy) * W + 4);
        float4 b2 = *reinterpret_cast<const float4*>(d2 + base0 + (2 * yy + 1) * W);
        float4 b3 = *reinterpret_cast<const float4*>(d2 + base0 + (2 * yy + 1) * W + 4);
        float ra[2][8] = {{a0.x,a0.y,a0.z,a0.w,a1.x,a1.y,a1.z,a1.w},
                          {a2.x,a2.y,a2.z,a2.w,a3.x,a3.y,a3.z,a3.w}};
        float rb[2][8] = {{b0.x,b0.y,b0.z,b0.w,b1.x,b1.y,b1.z,b1.w},
                          {b2.x,b2.y,b2.z,b2.w,b3.x,b3.y,b3.z,b3.w}};
        #pragma unroll
        for (int e = 0; e < 2; ++e) {
            float o[8];
            #pragma unroll
            for (int xx = 0; xx < 8; ++xx) o[xx] = w0 * expf(-fabsf(ra[e][xx] - rb[e][xx]));
            *reinterpret_cast<float4*>(dt0 + base0 + (2 * yy + e) * W)     = make_float4(o[0], o[1], o[2], o[3]);
            *reinterpret_cast<float4*>(dt0 + base0 + (2 * yy + e) * W + 4) = make_float4(o[4], o[5], o[6], o[7]);
        }
        #pragma unroll
        for (int xx = 0; xx < 4; ++xx) {
            q1[yy][xx] = 0.25f * (ra[0][2 * xx] + ra[0][2 * xx + 1] + ra[1][2 * xx] + ra[1][2 * xx + 1]);
            q2[yy][xx] = 0.25f * (rb[0][2 * xx] + rb[0][2 * xx + 1] + rb[1][2 * xx] + rb[1][2 * xx + 1]);
        }
    }
    #pragma unroll
    for (int yy = 0; yy < 4; ++yy)
        #pragma unroll
        for (int xx = 0; xx < 4; ++xx)
            dt1[((size_t)b * 64 + ry * 4 + yy) * 96 + rx * 4 + xx] = w0 * expf(-fabsf(q1[yy][xx] - q2[yy][xx]));

    float r1[2][2], r2m[2][2];
    #pragma unroll
    for (int y = 0; y < 2; ++y)
        #pragma unroll
        for (int x = 0; x < 2; ++x) {
            r1[y][x]  = 0.25f * (q1[2 * y][2 * x] + q1[2 * y][2 * x + 1] + q1[2 * y + 1][2 * x] + q1[2 * y + 1][2 * x + 1]);
            r2m[y][x] = 0.25f * (q2[2 * y][2 * x] + q2[2 * y][2 * x + 1] + q2[2 * y + 1][2 * x] + q2[2 * y + 1][2 * x + 1]);
            dt2[((size_t)b * 32 + ry * 2 + y) * 48 + rx * 2 + x] = w0 * expf(-fabsf(r1[y][x] - r2m[y][x]));
        }
    float s1 = 0.25f * (r1[0][0] + r1[0][1] + r1[1][0] + r1[1][1]);
    float s2 = 0.25f * (r2m[0][0] + r2m[0][1] + r2m[1][0] + r2m[1][1]);
    dt3[((size_t)b * 16 + ry) * 24 + rx] = w0 * expf(-fabsf(s1 - s2));
}

// =====================================================================
extern "C" void kernel_launch(void* const* d_in, const int* in_sizes, int n_in,
                              void* d_out, int out_size, void* d_ws, size_t ws_size,
                              hipStream_t stream) {
    const float* f1 = (const float*)d_in[0];
    const float* f2 = (const float*)d_in[1];
    const float* d1 = (const float*)d_in[2];
    const float* d2 = (const float*)d_in[3];
    const float* dw = (const float*)d_in[4];
    float* out = (float*)d_out;
    float* ws  = (float*)d_ws;

    // ---------------- float workspace carve ----------------
    size_t o = 0;
    float* in1_0 = ws + o; o += (size_t)4 * 128 * 192;
    float* in1_1 = ws + o; o += (size_t)4 * 64 * 96;
    float* in1_2 = ws + o; o += (size_t)4 * 32 * 48;
    float* in1_3 = ws + o; o += (size_t)4 * 16 * 24;
    float* in2_0 = ws + o; o += (size_t)4 * 128 * 192;
    float* in2_1 = ws + o; o += (size_t)4 * 64 * 96;
    float* in2_2 = ws + o; o += (size_t)4 * 32 * 48;
    float* in2_3 = ws + o; o += (size_t)4 * 16 * 24;
    float* dt_0 = ws + o; o += (size_t)4 * 128 * 192;
    float* dt_1 = ws + o; o += (size_t)4 * 64 * 96;
    float* dt_2 = ws + o; o += (size_t)4 * 32 * 48;
    float* dt_3 = ws + o; o += (size_t)4 * 16 * 24;
    o = (o + 7) & ~(size_t)7;

    // ---------------- bf16 (ushort) workspace carve ----------------
    ushort_t* sws = (ushort_t*)(ws + o);
    const size_t L0 = (size_t)4 * 128 * 192 * 256;
    const size_t L1 = (size_t)4 * 64 * 96 * 256;
    const size_t L2 = (size_t)4 * 32 * 48 * 256;
    const size_t L3 = (size_t)4 * 16 * 24 * 256;
    const size_t FT = L0 + L1 + L2 + L3;
    ushort_t* f1n0 = sws;
    ushort_t* f1n1 = f1n0 + L0;
    ushort_t* f1n2 = f1n1 + L1;
    ushort_t* f1n3 = f1n2 + L2;
    ushort_t* f2n0 = sws + FT;
    ushort_t* f2n1 = f2n0 + L0;
    ushort_t* f2n2 = f2n1 + L1;
    ushort_t* f2n3 = f2n2 + L2;
    ushort_t* zblk = sws + 2 * FT;
    size_t need = o * 4 + (2 * FT + 256) * 2;
    if (ws_size < need) return;   // proven sufficient in prior rounds

    hipMemsetAsync(zblk, 0, 512, stream);

    depth_kernel<<<dim3(6), 256, 0, stream>>>(d1, d2, dw, dt_0, dt_1, dt_2, dt_3);

    PrepPtrs Pa = { f1n0, f1n1, f1n2, f1n3, in1_0, in1_1, in1_2, in1_3 };
    PrepPtrs Pb = { f2n0, f2n1, f2n2, f2n3, in2_0, in2_1, in2_2, in2_3 };
    pyr_prep_kernel<<<dim3(384, 2), 256, 0, stream>>>(f1, f2, Pa, Pb);

    corr_mfma2_kernel<<<dim3(16 * 12 * 4), 256, 0, stream>>>(f1n0, f2n0, in1_0, in2_0, dt_0, out,           zblk, 128, 192, 12, 16, NP32_0);
    corr_mfma2_kernel<<<dim3( 8 *  6 * 4), 256, 0, stream>>>(f1n1, f2n1, in1_1, in2_1, dt_1, out + 7962624, zblk,  64,  96,  6,  8, NP32_1);
    corr_mfma2_kernel<<<dim3( 4 *  3 * 4), 256, 0, stream>>>(f1n2, f2n2, in1_2, in2_2, dt_2, out + 9953280, zblk,  32,  48,  3,  4, NP32_2);
    corr_mfma_kernel<<<dim3(96 / 4), 256, 0, stream>>>(f1n3, f2n3, in1_3, in2_3, dt_3, out + 10450944, 16, 24, 6, 4,
                                                       (int)(2 * FT - (size_t)(f2n3 - sws)));
}

// Round 9
// 276.652 us; speedup vs baseline: 1.1469x; 1.1469x over previous
//
#include <hip/hip_runtime.h>
#include <hip/hip_bf16.h>

typedef __attribute__((ext_vector_type(8))) __bf16 bf16x8;
typedef __attribute__((ext_vector_type(4))) float f32x4;
typedef unsigned short ushort_t;
typedef unsigned int uint_t;

#define CCH 256
#define BB 4

// kc-plane strides in shorts: level npix * 32 ch
#define NP32_0 3145728   // 4*128*192*32
#define NP32_1 786432    // 4*64*96*32
#define NP32_2 196608    // 4*32*48*32
#define NP32_3 49152     // 4*16*24*32

__device__ __forceinline__ ushort_t f2b(float v) {
    __hip_bfloat16 h = __float2bfloat16(v);
    return *reinterpret_cast<ushort_t*>(&h);
}

__device__ __forceinline__ void gload16(const void* g, void* l) {
    __builtin_amdgcn_global_load_lds(
        (const __attribute__((address_space(1))) void*)g,
        (__attribute__((address_space(3))) void*)l, 16, 0, 0);
}

struct PrepPtrs {
    ushort_t* o0; ushort_t* o1; ushort_t* o2; ushort_t* o3;
    float* n0; float* n1; float* n2; float* n3;
};

// =====================================================================
// pyr_prep v3 (EXACT round-6 kernel — best measured config, 135us).
// [c][p+pad] LDS, kc-blocked bf16 output, plain stores.
// =====================================================================
__global__ __launch_bounds__(256, 3) void pyr_prep_kernel(
    const float* __restrict__ fa, const float* __restrict__ fb,
    PrepPtrs Pa, PrepPtrs Pb)
{
    const int H = 128, W = 192;
    const int HW = H * W;
    const float* fin = blockIdx.y ? fb : fa;
    PrepPtrs P = blockIdx.y ? Pb : Pa;

    __shared__ float lds0[32 * 260];   // [c:32][p:256 pad->260]
    __shared__ float lds1[32 * 68];    // [c:32][q:64 pad->68]
    __shared__ float lds2[32 * 20];    // [c:32][s:16 pad->20]
    __shared__ float red[256];

    int xc = blockIdx.x % 6;
    int ys = (blockIdx.x / 6) % 16;
    int b  = blockIdx.x / 96;
    int gx0 = xc * 32, gy0 = ys * 8;
    int t = threadIdx.x;

    const float* gsrc[8];
    int lofs[8];
    #pragma unroll
    for (int j = 0; j < 8; ++j) {
        int e = t + 256 * j;
        int c = e >> 6, r = (e >> 3) & 7, x4 = e & 7;
        gsrc[j] = fin + ((size_t)(b * 256 + c) * H + gy0 + r) * W + gx0 + 4 * x4;
        lofs[j] = c * 260 + r * 32 + 4 * x4;
    }

    float4 stg[8];
    auto issue = [&](int kc) {
        #pragma unroll
        for (int j = 0; j < 8; ++j)
            stg[j] = *reinterpret_cast<const float4*>(gsrc[j] + (size_t)kc * (32 * HW));
    };

    float ssq0 = 0.f, ssq1 = 0.f, ssq2 = 0.f, ssq3 = 0.f;

    size_t p0g = (size_t)(b * H + gy0 + (t >> 5)) * W + gx0 + (t & 31);     // L0 pixel
    int wv = t >> 6, q = t & 63, qy = q >> 4, qx = q & 15;                  // L1
    size_t l1g = (size_t)(b * 64 + ys * 4 + qy) * 96 + xc * 16 + qx;
    int cb2 = t >> 4, sI = t & 15, sy2 = sI >> 3, sx2 = sI & 7;             // L2 (t<128)
    size_t l2g = (size_t)(b * 32 + ys * 2 + sy2) * 48 + xc * 8 + sx2;
    int cb3 = t >> 2, u3 = t & 3;                                           // L3 (t<32)
    size_t l3g = (size_t)(b * 16 + ys) * 24 + xc * 4 + u3;

    issue(0);
    #pragma unroll 1
    for (int kc = 0; kc < 8; ++kc) {
        // ---- A: regs -> lds0 (b128, conflict-free) ----
        #pragma unroll
        for (int j = 0; j < 8; ++j)
            *reinterpret_cast<float4*>(&lds0[lofs[j]]) = stg[j];
        if (kc < 7) issue(kc + 1);
        __syncthreads();

        // ---- B: L0 bf16 (blocked layout: kc-plane + pixel*32) ----
        {
            uint_t uu[16];
            #pragma unroll
            for (int i = 0; i < 16; ++i) {
                float va = lds0[(2 * i) * 260 + t];
                float vb = lds0[(2 * i + 1) * 260 + t];
                ssq0 = fmaf(va, va, ssq0);
                ssq0 = fmaf(vb, vb, ssq0);
                uu[i] = (uint_t)f2b(va) | ((uint_t)f2b(vb) << 16);
            }
            ushort_t* dst = P.o0 + (size_t)kc * NP32_0 + p0g * 32;
            *reinterpret_cast<uint4*>(dst +  0) = make_uint4(uu[0],  uu[1],  uu[2],  uu[3]);
            *reinterpret_cast<uint4*>(dst +  8) = make_uint4(uu[4],  uu[5],  uu[6],  uu[7]);
            *reinterpret_cast<uint4*>(dst + 16) = make_uint4(uu[8],  uu[9],  uu[10], uu[11]);
            *reinterpret_cast<uint4*>(dst + 24) = make_uint4(uu[12], uu[13], uu[14], uu[15]);
        }

        // ---- L1: 2x2 pool ----
        {
            float a8[8];
            #pragma unroll
            for (int h = 0; h < 8; ++h) {
                int c = wv * 8 + h;
                float2 s0 = *reinterpret_cast<const float2*>(&lds0[c * 260 + (2 * qy) * 32 + 2 * qx]);
                float2 s1 = *reinterpret_cast<const float2*>(&lds0[c * 260 + (2 * qy + 1) * 32 + 2 * qx]);
                a8[h] = 0.25f * (s0.x + s0.y + s1.x + s1.y);
                ssq1 = fmaf(a8[h], a8[h], ssq1);
            }
            uint_t vv[4];
            #pragma unroll
            for (int i = 0; i < 4; ++i)
                vv[i] = (uint_t)f2b(a8[2 * i]) | ((uint_t)f2b(a8[2 * i + 1]) << 16);
            *reinterpret_cast<uint4*>(P.o1 + (size_t)kc * NP32_1 + l1g * 32 + wv * 8)
                = make_uint4(vv[0], vv[1], vv[2], vv[3]);
            #pragma unroll
            for (int h = 0; h < 8; ++h)
                lds1[(wv * 8 + h) * 68 + q] = a8[h];
        }
        __syncthreads();

        // ---- L2: 2x2 pool (t<128) ----
        if (t < 128) {
            float a4[4];
            #pragma unroll
            for (int cc = 0; cc < 4; ++cc) {
                int c = cb2 * 4 + cc;
                float2 s0 = *reinterpret_cast<const float2*>(&lds1[c * 68 + (2 * sy2) * 16 + 2 * sx2]);
                float2 s1 = *reinterpret_cast<const float2*>(&lds1[c * 68 + (2 * sy2 + 1) * 16 + 2 * sx2]);
                a4[cc] = 0.25f * (s0.x + s0.y + s1.x + s1.y);
                ssq2 = fmaf(a4[cc], a4[cc], ssq2);
            }
            uint_t w0 = (uint_t)f2b(a4[0]) | ((uint_t)f2b(a4[1]) << 16);
            uint_t w1 = (uint_t)f2b(a4[2]) | ((uint_t)f2b(a4[3]) << 16);
            *reinterpret_cast<uint2*>(P.o2 + (size_t)kc * NP32_2 + l2g * 32 + cb2 * 4) = make_uint2(w0, w1);
            #pragma unroll
            for (int cc = 0; cc < 4; ++cc)
                lds2[(cb2 * 4 + cc) * 20 + sI] = a4[cc];
        }
        __syncthreads();

        // ---- L3: 2x2 pool (t<32) ----
        if (t < 32) {
            float a4[4];
            #pragma unroll
            for (int cc = 0; cc < 4; ++cc) {
                int c = cb3 * 4 + cc;
                float2 s0 = *reinterpret_cast<const float2*>(&lds2[c * 20 + 2 * u3]);
                float2 s1 = *reinterpret_cast<const float2*>(&lds2[c * 20 + 8 + 2 * u3]);
                a4[cc] = 0.25f * (s0.x + s0.y + s1.x + s1.y);
                ssq3 = fmaf(a4[cc], a4[cc], ssq3);
            }
            uint_t w0 = (uint_t)f2b(a4[0]) | ((uint_t)f2b(a4[1]) << 16);
            uint_t w1 = (uint_t)f2b(a4[2]) | ((uint_t)f2b(a4[3]) << 16);
            *reinterpret_cast<uint2*>(P.o3 + (size_t)kc * NP32_3 + l3g * 32 + cb3 * 4) = make_uint2(w0, w1);
        }
    }

    // ---- invnorm reductions ----
    P.n0[p0g] = 1.f / fmaxf(sqrtf(ssq0), 1e-12f);
    red[t] = ssq1;
    __syncthreads();
    if (t < 64) {
        float sm = red[t] + red[t + 64] + red[t + 128] + red[t + 192];
        P.n1[(size_t)(b * 64 + ys * 4 + (t >> 4)) * 96 + xc * 16 + (t & 15)]
            = 1.f / fmaxf(sqrtf(sm), 1e-12f);
    }
    __syncthreads();
    if (t < 128) red[t] = ssq2;
    __syncthreads();
    if (t < 16) {
        float sm = 0.f;
        #pragma unroll
        for (int c = 0; c < 8; ++c) sm += red[t + 16 * c];
        P.n2[(size_t)(b * 32 + ys * 2 + (t >> 3)) * 48 + xc * 8 + (t & 7)]
            = 1.f / fmaxf(sqrtf(sm), 1e-12f);
    }
    __syncthreads();
    if (t < 32) red[t] = ssq3;
    __syncthreads();
    if (t < 4) {
        float sm = 0.f;
        #pragma unroll
        for (int c = 0; c < 8; ++c) sm += red[t + 4 * c];
        P.n3[(size_t)(b * 16 + ys) * 24 + xc * 4 + t]
            = 1.f / fmaxf(sqrtf(sm), 1e-12f);
    }
}

// =====================================================================
// corr_mfma2 v2: counted vmcnt(8) pipeline (T4) — the ONLY change vs r6.
// Next-chunk loads stay in flight across barrier 1; no full drain.
// =====================================================================
__global__ __launch_bounds__(256, 2) void corr_mfma2_kernel(
    const ushort_t* __restrict__ f1n, const ushort_t* __restrict__ f2n,
    const float* __restrict__ invn1, const float* __restrict__ invn2,
    const float* __restrict__ dt, float* __restrict__ out,
    const ushort_t* __restrict__ zblk, int H, int W, int TX, int TY, int npix32)
{
    __shared__ char smem[65536];
    char* As = smem;
    char* Bs = smem + 16384;

    int bid = blockIdx.x;
    int cpx = gridDim.x >> 3;
    int swz = (bid & 7) * cpx + (bid >> 3);
    int tx = swz % TX;
    int ty = (swz / TX) % TY;
    int b  = swz / (TX * TY);
    int x0 = tx * 16, y0 = ty * 8;

    int tid = threadIdx.x;
    int w = tid >> 6, lane = tid & 63;
    int kg = lane >> 4, col = lane & 15;
    int r2 = col >> 2, c2 = col & 3;
    int sy = w >> 1, p = w & 1;

    const ushort_t* srcA[2]; char* ldsA[2];
    #pragma unroll
    for (int q = 0; q < 2; ++q) {
        int qq = w * 2 + q;
        int kgs = qq >> 1, reg = qq & 1;
        int slot = reg * 64 + lane;
        int ly = slot >> 4, lxp = slot & 15;
        int lx = lxp ^ (4 * (ly & 1));
        srcA[q] = f1n + ((size_t)((b * H + y0 + ly) * W) + x0 + lx) * 32 + kgs * 8;
        ldsA[q] = As + qq * 1024;
    }
    const ushort_t* srcB[6]; int advB[6]; char* ldsB[6];
    #pragma unroll
    for (int q = 0; q < 6; ++q) {
        int qq = w * 6 + q;
        int kgs = qq / 6, reg = qq % 6;
        int slot = reg * 64 + lane;
        int wy = slot / 24, wxp = slot % 24;
        int wx = wxp ^ (4 * (wy & 1));
        int py = y0 - 4 + wy, px = x0 - 4 + wx;
        bool v = (py >= 0) && (py < H) && (px >= 0) && (px < W);
        srcB[q] = v ? (f2n + ((size_t)((b * H + py) * W) + px) * 32 + kgs * 8) : zblk;
        advB[q] = v ? npix32 : 0;
        ldsB[q] = Bs + qq * 1024;
    }

    int aoff[2], boff[3][4];
    #pragma unroll
    for (int s = 0; s < 2; ++s) {
        int sxs = 2 * p + s;
        int ly = 4 * sy + r2;
        int lx = (4 * sxs + c2) ^ (4 * (ly & 1));
        aoff[s] = kg * 2048 + (ly * 16 + lx) * 16;
    }
    #pragma unroll
    for (int i = 0; i < 3; ++i)
        #pragma unroll
        for (int j = 0; j < 4; ++j) {
            int wy = 4 * (sy + i) + r2;
            int wx = (4 * (2 * p + j) + c2) ^ (4 * (wy & 1));
            boff[i][j] = kg * 6144 + (wy * 24 + wx) * 16;
        }

    f32x4 acc0[3][3] = {};
    f32x4 acc1[3][3] = {};

    // prologue: issue chunk 0 into buf 0
    #pragma unroll
    for (int q = 0; q < 2; ++q) { gload16(srcA[q], ldsA[q]); srcA[q] += npix32; }
    #pragma unroll
    for (int q = 0; q < 6; ++q) { gload16(srcB[q], ldsB[q]); srcB[q] += advB[q]; }

    int buf = 0;
    #pragma unroll 1
    for (int kc = 0; kc < 8; ++kc) {
        if (kc < 7) {
            int boA = (buf ^ 1) * 8192;
            int boB = (buf ^ 1) * 24576;
            #pragma unroll
            for (int q = 0; q < 2; ++q) { gload16(srcA[q], ldsA[q] + boA); srcA[q] += npix32; }
            #pragma unroll
            for (int q = 0; q < 6; ++q) { gload16(srcB[q], ldsB[q] + boB); srcB[q] += advB[q]; }
            __builtin_amdgcn_sched_barrier(0);
            asm volatile("s_waitcnt vmcnt(8)" ::: "memory");   // cur buf's 8 landed; next 8 in flight
        } else {
            __builtin_amdgcn_sched_barrier(0);
            asm volatile("s_waitcnt vmcnt(0)" ::: "memory");
        }
        __builtin_amdgcn_s_barrier();          // barrier 1: cur buf ready for all waves
        __builtin_amdgcn_sched_barrier(0);

        const char* Ab = As + buf * 8192;
        const char* Bb = Bs + buf * 24576;
        bf16x8 av0 = *(const bf16x8*)(Ab + aoff[0]);
        bf16x8 av1 = *(const bf16x8*)(Ab + aoff[1]);
        #pragma unroll
        for (int i = 0; i < 3; ++i) {
            #pragma unroll
            for (int j = 0; j < 4; ++j) {
                bf16x8 bv = *(const bf16x8*)(Bb + boff[i][j]);
                if (j < 3) acc0[i][j]     = __builtin_amdgcn_mfma_f32_16x16x32_bf16(av0, bv, acc0[i][j], 0, 0, 0);
                if (j > 0) acc1[i][j - 1] = __builtin_amdgcn_mfma_f32_16x16x32_bf16(av1, bv, acc1[i][j - 1], 0, 0, 0);
            }
        }
        if (kc < 7) {
            __builtin_amdgcn_sched_barrier(0);
            __builtin_amdgcn_s_barrier();      // barrier 2: all waves done reading buf
            __builtin_amdgcn_sched_barrier(0);
        }
        buf ^= 1;
    }

    float inv1v[2][4], dtv[2][4];
    #pragma unroll
    for (int s = 0; s < 2; ++s) {
        int sxs = 2 * p + s;
        #pragma unroll
        for (int rr = 0; rr < 4; ++rr) {
            int m = kg * 4 + rr;
            int iy = m >> 2, ix = m & 3;
            int pix = (b * H + y0 + 4 * sy + iy) * W + x0 + 4 * sxs + ix;
            inv1v[s][rr] = invn1[pix];
            dtv[s][rr]   = dt[pix];
        }
    }
    #pragma unroll
    for (int s = 0; s < 2; ++s) {
        int sxs = 2 * p + s;
        #pragma unroll
        for (int i = 0; i < 3; ++i) {
            #pragma unroll
            for (int jj = 0; jj < 3; ++jj) {
                int wy = 4 * (sy + i) + r2;
                int wxr = 4 * (sxs + jj) + c2;
                int py = y0 - 4 + wy, px = x0 - 4 + wxr;
                bool v = (py >= 0) && (py < H) && (px >= 0) && (px < W);
                float i2 = v ? invn2[(b * H + py) * W + px] : 0.f;
                f32x4 a = (s == 0) ? acc0[i][jj] : acc1[i][jj];
                #pragma unroll
                for (int rr = 0; rr < 4; ++rr) {
                    int m = kg * 4 + rr;
                    int iy = m >> 2, ix = m & 3;
                    int oy = iy + 8 - (4 * i + r2);
                    int ox = ix + 8 - (4 * jj + c2);
                    if (oy >= 0 && oy < 9 && ox >= 0 && ox < 9) {
                        int gy = y0 + 4 * sy + iy, gx = x0 + 4 * sxs + ix;
                        out[((size_t)(b * 81 + oy * 9 + ox) * H + gy) * W + gx]
                            = a[rr] * inv1v[s][rr] * i2 + dtv[s][rr];
                    }
                }
            }
        }
    }
}

// =====================================================================
// corr_mfma — L3 only, kc-blocked layout
// =====================================================================
__global__ __launch_bounds__(256) void corr_mfma_kernel(
    const ushort_t* __restrict__ f1n, const ushort_t* __restrict__ f2n,
    const float* __restrict__ invn1, const float* __restrict__ invn2,
    const float* __restrict__ dt, float* __restrict__ out,
    int H, int W, int TX, int TY, int zoff)
{
    int wid  = threadIdx.x >> 6;
    int lane = threadIdx.x & 63;
    int tile = blockIdx.x * 4 + wid;
    int ntiles = BB * TY * TX;
    if (tile >= ntiles) return;
    int tx = tile % TX;
    int ty = (tile / TX) % TY;
    int b  = tile / (TX * TY);
    int x0 = tx * 4, y0 = ty * 4;

    int col = lane & 15;
    int kg  = lane >> 4;

    int iyA = col >> 2, ixA = col & 3;
    int a_off = (((b * H + y0 + iyA) * W) + x0 + ixA) * 32 + kg * 8;

    int b_off[9], badv[9];
    uint_t vmask = 0;
    #pragma unroll
    for (int tt = 0; tt < 9; ++tt) {
        int w = tt * 16 + col;
        int wy = w / 12, wx = w % 12;
        int py = y0 + wy - 4, px = x0 + wx - 4;
        bool v = (py >= 0) && (py < H) && (px >= 0) && (px < W);
        b_off[tt] = v ? (((b * H + py) * W + px) * 32 + kg * 8) : (zoff + kg * 8);
        badv[tt] = v ? NP32_3 : 0;
        if (v) vmask |= (1u << tt);
    }

    f32x4 acc[9] = {};
    #pragma unroll
    for (int kb = 0; kb < 8; ++kb) {
        bf16x8 av = *reinterpret_cast<const bf16x8*>(f1n + a_off + kb * NP32_3);
        #pragma unroll
        for (int tt = 0; tt < 9; ++tt) {
            bf16x8 bv = *reinterpret_cast<const bf16x8*>(f2n + b_off[tt]);
            acc[tt] = __builtin_amdgcn_mfma_f32_16x16x32_bf16(av, bv, acc[tt], 0, 0, 0);
            b_off[tt] += badv[tt];
        }
    }

    float inv1[4], dts[4];
    #pragma unroll
    for (int r = 0; r < 4; ++r) {
        int m = kg * 4 + r;
        int iy = m >> 2, ix = m & 3;
        int pix = (b * H + y0 + iy) * W + x0 + ix;
        inv1[r] = invn1[pix];
        dts[r]  = dt[pix];
    }
    #pragma unroll
    for (int tt = 0; tt < 9; ++tt) {
        int w = tt * 16 + col;
        int wy = w / 12, wx = w % 12;
        int py = y0 + wy - 4, px = x0 + wx - 4;
        float i2 = ((vmask >> tt) & 1u) ? invn2[(b * H + py) * W + px] : 0.f;
        #pragma unroll
        for (int r = 0; r < 4; ++r) {
            int m = kg * 4 + r;
            int iy = m >> 2, ix = m & 3;
            int oy = iy + 8 - wy, ox = ix + 8 - wx;
            if (oy >= 0 && oy < 9 && ox >= 0 && ox < 9) {
                int o = oy * 9 + ox;
                out[((size_t)(b * 81 + o) * H + (y0 + iy)) * W + (x0 + ix)]
                    = acc[tt][r] * inv1[r] * i2 + dts[r];
            }
        }
    }
}

// =====================================================================
// depth: one thread owns an 8x8 L0 patch; dt for all 4 levels
// =====================================================================
__global__ __launch_bounds__(256) void depth_kernel(
    const float* __restrict__ d1, const float* __restrict__ d2,
    const float* __restrict__ dw,
    float* __restrict__ dt0, float* __restrict__ dt1,
    float* __restrict__ dt2, float* __restrict__ dt3)
{
    int rid = blockIdx.x * 256 + threadIdx.x;
    if (rid >= 4 * 16 * 24) return;
    int b = rid / 384, rr = rid % 384, ry = rr / 24, rx = rr % 24;
    const int H = 128, W = 192;
    float w0 = dw[0];
    size_t base0 = ((size_t)b * H + ry * 8) * W + rx * 8;

    float q1[4][4], q2[4][4];
    #pragma unroll
    for (int yy = 0; yy < 4; ++yy) {
        float4 a0 = *reinterpret_cast<const float4*>(d1 + base0 + (2 * yy) * W);
        float4 a1 = *reinterpret_cast<const float4*>(d1 + base0 + (2 * yy) * W + 4);
        float4 a2 = *reinterpret_cast<const float4*>(d1 + base0 + (2 * yy + 1) * W);
        float4 a3 = *reinterpret_cast<const float4*>(d1 + base0 + (2 * yy + 1) * W + 4);
        float4 b0 = *reinterpret_cast<const float4*>(d2 + base0 + (2 * yy) * W);
        float4 b1 = *reinterpret_cast<const float4*>(d2 + base0 + (2 * yy) * W + 4);
        float4 b2 = *reinterpret_cast<const float4*>(d2 + base0 + (2 * yy + 1) * W);
        float4 b3 = *reinterpret_cast<const float4*>(d2 + base0 + (2 * yy + 1) * W + 4);
        float ra[2][8] = {{a0.x,a0.y,a0.z,a0.w,a1.x,a1.y,a1.z,a1.w},
                          {a2.x,a2.y,a2.z,a2.w,a3.x,a3.y,a3.z,a3.w}};
        float rb[2][8] = {{b0.x,b0.y,b0.z,b0.w,b1.x,b1.y,b1.z,b1.w},
                          {b2.x,b2.y,b2.z,b2.w,b3.x,b3.y,b3.z,b3.w}};
        #pragma unroll
        for (int e = 0; e < 2; ++e) {
            float o[8];
            #pragma unroll
            for (int xx = 0; xx < 8; ++xx) o[xx] = w0 * expf(-fabsf(ra[e][xx] - rb[e][xx]));
            *reinterpret_cast<float4*>(dt0 + base0 + (2 * yy + e) * W)     = make_float4(o[0], o[1], o[2], o[3]);
            *reinterpret_cast<float4*>(dt0 + base0 + (2 * yy + e) * W + 4) = make_float4(o[4], o[5], o[6], o[7]);
        }
        #pragma unroll
        for (int xx = 0; xx < 4; ++xx) {
            q1[yy][xx] = 0.25f * (ra[0][2 * xx] + ra[0][2 * xx + 1] + ra[1][2 * xx] + ra[1][2 * xx + 1]);
            q2[yy][xx] = 0.25f * (rb[0][2 * xx] + rb[0][2 * xx + 1] + rb[1][2 * xx] + rb[1][2 * xx + 1]);
        }
    }
    #pragma unroll
    for (int yy = 0; yy < 4; ++yy)
        #pragma unroll
        for (int xx = 0; xx < 4; ++xx)
            dt1[((size_t)b * 64 + ry * 4 + yy) * 96 + rx * 4 + xx] = w0 * expf(-fabsf(q1[yy][xx] - q2[yy][xx]));

    float r1[2][2], r2m[2][2];
    #pragma unroll
    for (int y = 0; y < 2; ++y)
        #pragma unroll
        for (int x = 0; x < 2; ++x) {
            r1[y][x]  = 0.25f * (q1[2 * y][2 * x] + q1[2 * y][2 * x + 1] + q1[2 * y + 1][2 * x] + q1[2 * y + 1][2 * x + 1]);
            r2m[y][x] = 0.25f * (q2[2 * y][2 * x] + q2[2 * y][2 * x + 1] + q2[2 * y + 1][2 * x] + q2[2 * y + 1][2 * x + 1]);
            dt2[((size_t)b * 32 + ry * 2 + y) * 48 + rx * 2 + x] = w0 * expf(-fabsf(r1[y][x] - r2m[y][x]));
        }
    float s1 = 0.25f * (r1[0][0] + r1[0][1] + r1[1][0] + r1[1][1]);
    float s2 = 0.25f * (r2m[0][0] + r2m[0][1] + r2m[1][0] + r2m[1][1]);
    dt3[((size_t)b * 16 + ry) * 24 + rx] = w0 * expf(-fabsf(s1 - s2));
}

// =====================================================================
extern "C" void kernel_launch(void* const* d_in, const int* in_sizes, int n_in,
                              void* d_out, int out_size, void* d_ws, size_t ws_size,
                              hipStream_t stream) {
    const float* f1 = (const float*)d_in[0];
    const float* f2 = (const float*)d_in[1];
    const float* d1 = (const float*)d_in[2];
    const float* d2 = (const float*)d_in[3];
    const float* dw = (const float*)d_in[4];
    float* out = (float*)d_out;
    float* ws  = (float*)d_ws;

    // ---------------- float workspace carve ----------------
    size_t o = 0;
    float* in1_0 = ws + o; o += (size_t)4 * 128 * 192;
    float* in1_1 = ws + o; o += (size_t)4 * 64 * 96;
    float* in1_2 = ws + o; o += (size_t)4 * 32 * 48;
    float* in1_3 = ws + o; o += (size_t)4 * 16 * 24;
    float* in2_0 = ws + o; o += (size_t)4 * 128 * 192;
    float* in2_1 = ws + o; o += (size_t)4 * 64 * 96;
    float* in2_2 = ws + o; o += (size_t)4 * 32 * 48;
    float* in2_3 = ws + o; o += (size_t)4 * 16 * 24;
    float* dt_0 = ws + o; o += (size_t)4 * 128 * 192;
    float* dt_1 = ws + o; o += (size_t)4 * 64 * 96;
    float* dt_2 = ws + o; o += (size_t)4 * 32 * 48;
    float* dt_3 = ws + o; o += (size_t)4 * 16 * 24;
    o = (o + 7) & ~(size_t)7;

    // ---------------- bf16 (ushort) workspace carve ----------------
    ushort_t* sws = (ushort_t*)(ws + o);
    const size_t L0 = (size_t)4 * 128 * 192 * 256;
    const size_t L1 = (size_t)4 * 64 * 96 * 256;
    const size_t L2 = (size_t)4 * 32 * 48 * 256;
    const size_t L3 = (size_t)4 * 16 * 24 * 256;
    const size_t FT = L0 + L1 + L2 + L3;
    ushort_t* f1n0 = sws;
    ushort_t* f1n1 = f1n0 + L0;
    ushort_t* f1n2 = f1n1 + L1;
    ushort_t* f1n3 = f1n2 + L2;
    ushort_t* f2n0 = sws + FT;
    ushort_t* f2n1 = f2n0 + L0;
    ushort_t* f2n2 = f2n1 + L1;
    ushort_t* f2n3 = f2n2 + L2;
    ushort_t* zblk = sws + 2 * FT;
    size_t need = o * 4 + (2 * FT + 256) * 2;
    if (ws_size < need) return;   // proven sufficient in prior rounds

    hipMemsetAsync(zblk, 0, 512, stream);

    depth_kernel<<<dim3(6), 256, 0, stream>>>(d1, d2, dw, dt_0, dt_1, dt_2, dt_3);

    PrepPtrs Pa = { f1n0, f1n1, f1n2, f1n3, in1_0, in1_1, in1_2, in1_3 };
    PrepPtrs Pb = { f2n0, f2n1, f2n2, f2n3, in2_0, in2_1, in2_2, in2_3 };
    pyr_prep_kernel<<<dim3(384, 2), 256, 0, stream>>>(f1, f2, Pa, Pb);

    corr_mfma2_kernel<<<dim3(16 * 12 * 4), 256, 0, stream>>>(f1n0, f2n0, in1_0, in2_0, dt_0, out,           zblk, 128, 192, 12, 16, NP32_0);
    corr_mfma2_kernel<<<dim3( 8 *  6 * 4), 256, 0, stream>>>(f1n1, f2n1, in1_1, in2_1, dt_1, out + 7962624, zblk,  64,  96,  6,  8, NP32_1);
    corr_mfma2_kernel<<<dim3( 4 *  3 * 4), 256, 0, stream>>>(f1n2, f2n2, in1_2, in2_2, dt_2, out + 9953280, zblk,  32,  48,  3,  4, NP32_2);
    corr_mfma_kernel<<<dim3(96 / 4), 256, 0, stream>>>(f1n3, f2n3, in1_3, in2_3, dt_3, out + 10450944, 16, 24, 6, 4,
                                                       (int)(2 * FT - (size_t)(f2n3 - sws)));
}

// Round 10
// 241.222 us; speedup vs baseline: 1.3154x; 1.1469x over previous
//
#include <hip/hip_runtime.h>
#include <hip/hip_bf16.h>

typedef __attribute__((ext_vector_type(8))) __bf16 bf16x8;
typedef __attribute__((ext_vector_type(4))) float f32x4;
typedef unsigned short ushort_t;
typedef unsigned int uint_t;

#define CCH 256
#define BB 4

// kc-plane strides in shorts: level npix * 32 ch
#define NP32_0 3145728   // 4*128*192*32
#define NP32_1 786432    // 4*64*96*32
#define NP32_2 196608    // 4*32*48*32
#define NP32_3 49152     // 4*16*24*32

__device__ __forceinline__ ushort_t f2b(float v) {
    __hip_bfloat16 h = __float2bfloat16(v);
    return *reinterpret_cast<ushort_t*>(&h);
}

__device__ __forceinline__ void gload16(const void* g, void* l) {
    __builtin_amdgcn_global_load_lds(
        (const __attribute__((address_space(1))) void*)g,
        (__attribute__((address_space(3))) void*)l, 16, 0, 0);
}

struct PrepPtrs {
    ushort_t* o0; ushort_t* o1; ushort_t* o2; ushort_t* o3;
    float* n0; float* n1; float* n2; float* n3;
};

// =====================================================================
// pyr_prep (EXACT round-6/9 kernel — best measured, 133us). Unchanged.
// =====================================================================
__global__ __launch_bounds__(256, 3) void pyr_prep_kernel(
    const float* __restrict__ fa, const float* __restrict__ fb,
    PrepPtrs Pa, PrepPtrs Pb)
{
    const int H = 128, W = 192;
    const int HW = H * W;
    const float* fin = blockIdx.y ? fb : fa;
    PrepPtrs P = blockIdx.y ? Pb : Pa;

    __shared__ float lds0[32 * 260];
    __shared__ float lds1[32 * 68];
    __shared__ float lds2[32 * 20];
    __shared__ float red[256];

    int xc = blockIdx.x % 6;
    int ys = (blockIdx.x / 6) % 16;
    int b  = blockIdx.x / 96;
    int gx0 = xc * 32, gy0 = ys * 8;
    int t = threadIdx.x;

    const float* gsrc[8];
    int lofs[8];
    #pragma unroll
    for (int j = 0; j < 8; ++j) {
        int e = t + 256 * j;
        int c = e >> 6, r = (e >> 3) & 7, x4 = e & 7;
        gsrc[j] = fin + ((size_t)(b * 256 + c) * H + gy0 + r) * W + gx0 + 4 * x4;
        lofs[j] = c * 260 + r * 32 + 4 * x4;
    }

    float4 stg[8];
    auto issue = [&](int kc) {
        #pragma unroll
        for (int j = 0; j < 8; ++j)
            stg[j] = *reinterpret_cast<const float4*>(gsrc[j] + (size_t)kc * (32 * HW));
    };

    float ssq0 = 0.f, ssq1 = 0.f, ssq2 = 0.f, ssq3 = 0.f;

    size_t p0g = (size_t)(b * H + gy0 + (t >> 5)) * W + gx0 + (t & 31);
    int wv = t >> 6, q = t & 63, qy = q >> 4, qx = q & 15;
    size_t l1g = (size_t)(b * 64 + ys * 4 + qy) * 96 + xc * 16 + qx;
    int cb2 = t >> 4, sI = t & 15, sy2 = sI >> 3, sx2 = sI & 7;
    size_t l2g = (size_t)(b * 32 + ys * 2 + sy2) * 48 + xc * 8 + sx2;
    int cb3 = t >> 2, u3 = t & 3;
    size_t l3g = (size_t)(b * 16 + ys) * 24 + xc * 4 + u3;

    issue(0);
    #pragma unroll 1
    for (int kc = 0; kc < 8; ++kc) {
        #pragma unroll
        for (int j = 0; j < 8; ++j)
            *reinterpret_cast<float4*>(&lds0[lofs[j]]) = stg[j];
        if (kc < 7) issue(kc + 1);
        __syncthreads();

        {
            uint_t uu[16];
            #pragma unroll
            for (int i = 0; i < 16; ++i) {
                float va = lds0[(2 * i) * 260 + t];
                float vb = lds0[(2 * i + 1) * 260 + t];
                ssq0 = fmaf(va, va, ssq0);
                ssq0 = fmaf(vb, vb, ssq0);
                uu[i] = (uint_t)f2b(va) | ((uint_t)f2b(vb) << 16);
            }
            ushort_t* dst = P.o0 + (size_t)kc * NP32_0 + p0g * 32;
            *reinterpret_cast<uint4*>(dst +  0) = make_uint4(uu[0],  uu[1],  uu[2],  uu[3]);
            *reinterpret_cast<uint4*>(dst +  8) = make_uint4(uu[4],  uu[5],  uu[6],  uu[7]);
            *reinterpret_cast<uint4*>(dst + 16) = make_uint4(uu[8],  uu[9],  uu[10], uu[11]);
            *reinterpret_cast<uint4*>(dst + 24) = make_uint4(uu[12], uu[13], uu[14], uu[15]);
        }

        {
            float a8[8];
            #pragma unroll
            for (int h = 0; h < 8; ++h) {
                int c = wv * 8 + h;
                float2 s0 = *reinterpret_cast<const float2*>(&lds0[c * 260 + (2 * qy) * 32 + 2 * qx]);
                float2 s1 = *reinterpret_cast<const float2*>(&lds0[c * 260 + (2 * qy + 1) * 32 + 2 * qx]);
                a8[h] = 0.25f * (s0.x + s0.y + s1.x + s1.y);
                ssq1 = fmaf(a8[h], a8[h], ssq1);
            }
            uint_t vv[4];
            #pragma unroll
            for (int i = 0; i < 4; ++i)
                vv[i] = (uint_t)f2b(a8[2 * i]) | ((uint_t)f2b(a8[2 * i + 1]) << 16);
            *reinterpret_cast<uint4*>(P.o1 + (size_t)kc * NP32_1 + l1g * 32 + wv * 8)
                = make_uint4(vv[0], vv[1], vv[2], vv[3]);
            #pragma unroll
            for (int h = 0; h < 8; ++h)
                lds1[(wv * 8 + h) * 68 + q] = a8[h];
        }
        __syncthreads();

        if (t < 128) {
            float a4[4];
            #pragma unroll
            for (int cc = 0; cc < 4; ++cc) {
                int c = cb2 * 4 + cc;
                float2 s0 = *reinterpret_cast<const float2*>(&lds1[c * 68 + (2 * sy2) * 16 + 2 * sx2]);
                float2 s1 = *reinterpret_cast<const float2*>(&lds1[c * 68 + (2 * sy2 + 1) * 16 + 2 * sx2]);
                a4[cc] = 0.25f * (s0.x + s0.y + s1.x + s1.y);
                ssq2 = fmaf(a4[cc], a4[cc], ssq2);
            }
            uint_t w0 = (uint_t)f2b(a4[0]) | ((uint_t)f2b(a4[1]) << 16);
            uint_t w1 = (uint_t)f2b(a4[2]) | ((uint_t)f2b(a4[3]) << 16);
            *reinterpret_cast<uint2*>(P.o2 + (size_t)kc * NP32_2 + l2g * 32 + cb2 * 4) = make_uint2(w0, w1);
            #pragma unroll
            for (int cc = 0; cc < 4; ++cc)
                lds2[(cb2 * 4 + cc) * 20 + sI] = a4[cc];
        }
        __syncthreads();

        if (t < 32) {
            float a4[4];
            #pragma unroll
            for (int cc = 0; cc < 4; ++cc) {
                int c = cb3 * 4 + cc;
                float2 s0 = *reinterpret_cast<const float2*>(&lds2[c * 20 + 2 * u3]);
                float2 s1 = *reinterpret_cast<const float2*>(&lds2[c * 20 + 8 + 2 * u3]);
                a4[cc] = 0.25f * (s0.x + s0.y + s1.x + s1.y);
                ssq3 = fmaf(a4[cc], a4[cc], ssq3);
            }
            uint_t w0 = (uint_t)f2b(a4[0]) | ((uint_t)f2b(a4[1]) << 16);
            uint_t w1 = (uint_t)f2b(a4[2]) | ((uint_t)f2b(a4[3]) << 16);
            *reinterpret_cast<uint2*>(P.o3 + (size_t)kc * NP32_3 + l3g * 32 + cb3 * 4) = make_uint2(w0, w1);
        }
    }

    P.n0[p0g] = 1.f / fmaxf(sqrtf(ssq0), 1e-12f);
    red[t] = ssq1;
    __syncthreads();
    if (t < 64) {
        float sm = red[t] + red[t + 64] + red[t + 128] + red[t + 192];
        P.n1[(size_t)(b * 64 + ys * 4 + (t >> 4)) * 96 + xc * 16 + (t & 15)]
            = 1.f / fmaxf(sqrtf(sm), 1e-12f);
    }
    __syncthreads();
    if (t < 128) red[t] = ssq2;
    __syncthreads();
    if (t < 16) {
        float sm = 0.f;
        #pragma unroll
        for (int c = 0; c < 8; ++c) sm += red[t + 16 * c];
        P.n2[(size_t)(b * 32 + ys * 2 + (t >> 3)) * 48 + xc * 8 + (t & 7)]
            = 1.f / fmaxf(sqrtf(sm), 1e-12f);
    }
    __syncthreads();
    if (t < 32) red[t] = ssq3;
    __syncthreads();
    if (t < 4) {
        float sm = 0.f;
        #pragma unroll
        for (int c = 0; c < 8; ++c) sm += red[t + 4 * c];
        P.n3[(size_t)(b * 16 + ys) * 24 + xc * 4 + t]
            = 1.f / fmaxf(sqrtf(sm), 1e-12f);
    }
}

// =====================================================================
// corr_fused v3: L0+L1+L2 in ONE launch (1008 blocks -> 2 full rounds).
// Staging is LINEAR-SLOT: each gload16 instruction covers a contiguous
// ~1KB run (A tile = 8 insts of one row, B tile = 24 insts), fixing the
// 16B-per-64B-sector transaction blowup. LDS layout pixel-major
// [row][px][16B-chunk], with chunk index XORed by (px&3) symmetrically
// on the global source and the LDS fragment read (rule #21).
// =====================================================================
struct CorrLvl {
    const ushort_t* f1n; const ushort_t* f2n;
    const float* in1; const float* in2; const float* dt;
    float* out;
    int H, W, TX, TY, npix32;
};

__global__ __launch_bounds__(256, 2) void corr_fused_kernel(
    CorrLvl Lv0, CorrLvl Lv1, CorrLvl Lv2, const ushort_t* __restrict__ zblk)
{
    __shared__ char smem[65536];
    char* As = smem;            // 2 x 8KB
    char* Bs = smem + 16384;    // 2 x 24KB

    int bid = blockIdx.x;
    CorrLvl L;
    int local;
    if (bid < 768)      { L = Lv0; local = bid; }
    else if (bid < 960) { L = Lv1; local = bid - 768; }
    else                { L = Lv2; local = bid - 960; }

    int H = L.H, W = L.W, TX = L.TX, TY = L.TY, npix32 = L.npix32;
    int cpx = (BB * TX * TY) >> 3;
    int swz = (local & 7) * cpx + (local >> 3);
    int tx = swz % TX;
    int ty = (swz / TX) % TY;
    int b  = swz / (TX * TY);
    int x0 = tx * 16, y0 = ty * 8;

    int tid = threadIdx.x;
    int w = tid >> 6, lane = tid & 63;
    int kg = lane >> 4, col = lane & 15;
    int r2 = col >> 2, c2 = col & 3;
    int sy = w >> 1, p = w & 1;
    int kgx = kg ^ c2;   // swizzled chunk index for fragment reads

    // ---- A staging: 8 insts (one 1KB row each), wave w gets rows 2w,2w+1 ----
    const ushort_t* srcA[2]; char* ldsA[2];
    #pragma unroll
    for (int q = 0; q < 2; ++q) {
        int row = w * 2 + q;
        int px = lane >> 2, js = lane & 3;
        int j = js ^ (px & 3);
        srcA[q] = L.f1n + ((size_t)((b * H + y0 + row) * W) + x0 + px) * 32 + j * 8;
        ldsA[q] = As + row * 1024;
    }
    // ---- B staging: 24 insts (1536 16B units, rows of 96), wave w gets 6 ----
    const ushort_t* srcB[6]; int advB[6]; char* ldsB[6];
    #pragma unroll
    for (int q = 0; q < 6; ++q) {
        int u = (w * 6 + q) * 64 + lane;
        int row = u / 96, rem = u % 96;
        int px = rem >> 2, js = rem & 3;
        int j = js ^ (px & 3);
        int py = y0 - 4 + row, pxg = x0 - 4 + px;
        bool v = (py >= 0) && (py < H) && (pxg >= 0) && (pxg < W);
        srcB[q] = v ? (L.f2n + ((size_t)((b * H + py) * W) + pxg) * 32 + j * 8) : (zblk + j * 8);
        advB[q] = v ? npix32 : 0;
        ldsB[q] = Bs + (w * 6 + q) * 1024;
    }

    // ---- fragment LDS byte offsets (pixel-major, chunk XOR px&3) ----
    int aoff[2], boff[3][4];
    #pragma unroll
    for (int s = 0; s < 2; ++s) {
        int ly = 4 * sy + r2;
        int lx = 4 * (2 * p + s) + c2;
        aoff[s] = ((ly * 16 + lx) * 4 + kgx) * 16;
    }
    #pragma unroll
    for (int i = 0; i < 3; ++i)
        #pragma unroll
        for (int j = 0; j < 4; ++j) {
            int wy = 4 * (sy + i) + r2;
            int wx = 4 * (2 * p + j) + c2;
            boff[i][j] = ((wy * 24 + wx) * 4 + kgx) * 16;
        }

    f32x4 acc0[3][3] = {};
    f32x4 acc1[3][3] = {};

    // prologue: issue chunk 0 into buf 0
    #pragma unroll
    for (int q = 0; q < 2; ++q) { gload16(srcA[q], ldsA[q]); srcA[q] += npix32; }
    #pragma unroll
    for (int q = 0; q < 6; ++q) { gload16(srcB[q], ldsB[q]); srcB[q] += advB[q]; }

    int buf = 0;
    #pragma unroll 1
    for (int kc = 0; kc < 8; ++kc) {
        if (kc < 7) {
            int boA = (buf ^ 1) * 8192;
            int boB = (buf ^ 1) * 24576;
            #pragma unroll
            for (int q = 0; q < 2; ++q) { gload16(srcA[q], ldsA[q] + boA); srcA[q] += npix32; }
            #pragma unroll
            for (int q = 0; q < 6; ++q) { gload16(srcB[q], ldsB[q] + boB); srcB[q] += advB[q]; }
            __builtin_amdgcn_sched_barrier(0);
            asm volatile("s_waitcnt vmcnt(8)" ::: "memory");
        } else {
            __builtin_amdgcn_sched_barrier(0);
            asm volatile("s_waitcnt vmcnt(0)" ::: "memory");
        }
        __builtin_amdgcn_s_barrier();
        __builtin_amdgcn_sched_barrier(0);

        const char* Ab = As + buf * 8192;
        const char* Bb = Bs + buf * 24576;
        bf16x8 av0 = *(const bf16x8*)(Ab + aoff[0]);
        bf16x8 av1 = *(const bf16x8*)(Ab + aoff[1]);
        #pragma unroll
        for (int i = 0; i < 3; ++i) {
            #pragma unroll
            for (int j = 0; j < 4; ++j) {
                bf16x8 bv = *(const bf16x8*)(Bb + boff[i][j]);
                if (j < 3) acc0[i][j]     = __builtin_amdgcn_mfma_f32_16x16x32_bf16(av0, bv, acc0[i][j], 0, 0, 0);
                if (j > 0) acc1[i][j - 1] = __builtin_amdgcn_mfma_f32_16x16x32_bf16(av1, bv, acc1[i][j - 1], 0, 0, 0);
            }
        }
        if (kc < 7) {
            __builtin_amdgcn_sched_barrier(0);
            __builtin_amdgcn_s_barrier();
            __builtin_amdgcn_sched_barrier(0);
        }
        buf ^= 1;
    }

    float inv1v[2][4], dtv[2][4];
    #pragma unroll
    for (int s = 0; s < 2; ++s) {
        int sxs = 2 * p + s;
        #pragma unroll
        for (int rr = 0; rr < 4; ++rr) {
            int m = kg * 4 + rr;
            int iy = m >> 2, ix = m & 3;
            int pix = (b * H + y0 + 4 * sy + iy) * W + x0 + 4 * sxs + ix;
            inv1v[s][rr] = L.in1[pix];
            dtv[s][rr]   = L.dt[pix];
        }
    }
    #pragma unroll
    for (int s = 0; s < 2; ++s) {
        int sxs = 2 * p + s;
        #pragma unroll
        for (int i = 0; i < 3; ++i) {
            #pragma unroll
            for (int jj = 0; jj < 3; ++jj) {
                int wy = 4 * (sy + i) + r2;
                int wxr = 4 * (sxs + jj) + c2;
                int py = y0 - 4 + wy, px = x0 - 4 + wxr;
                bool v = (py >= 0) && (py < H) && (px >= 0) && (px < W);
                float i2 = v ? L.in2[(b * H + py) * W + px] : 0.f;
                f32x4 a = (s == 0) ? acc0[i][jj] : acc1[i][jj];
                #pragma unroll
                for (int rr = 0; rr < 4; ++rr) {
                    int m = kg * 4 + rr;
                    int iy = m >> 2, ix = m & 3;
                    int oy = iy + 8 - (4 * i + r2);
                    int ox = ix + 8 - (4 * jj + c2);
                    if (oy >= 0 && oy < 9 && ox >= 0 && ox < 9) {
                        int gy = y0 + 4 * sy + iy, gx = x0 + 4 * sxs + ix;
                        L.out[((size_t)(b * 81 + oy * 9 + ox) * H + gy) * W + gx]
                            = a[rr] * inv1v[s][rr] * i2 + dtv[s][rr];
                    }
                }
            }
        }
    }
}

// =====================================================================
// corr_mfma — L3 only, kc-blocked layout (unchanged)
// =====================================================================
__global__ __launch_bounds__(256) void corr_mfma_kernel(
    const ushort_t* __restrict__ f1n, const ushort_t* __restrict__ f2n,
    const float* __restrict__ invn1, const float* __restrict__ invn2,
    const float* __restrict__ dt, float* __restrict__ out,
    int H, int W, int TX, int TY, int zoff)
{
    int wid  = threadIdx.x >> 6;
    int lane = threadIdx.x & 63;
    int tile = blockIdx.x * 4 + wid;
    int ntiles = BB * TY * TX;
    if (tile >= ntiles) return;
    int tx = tile % TX;
    int ty = (tile / TX) % TY;
    int b  = tile / (TX * TY);
    int x0 = tx * 4, y0 = ty * 4;

    int col = lane & 15;
    int kg  = lane >> 4;

    int iyA = col >> 2, ixA = col & 3;
    int a_off = (((b * H + y0 + iyA) * W) + x0 + ixA) * 32 + kg * 8;

    int b_off[9], badv[9];
    uint_t vmask = 0;
    #pragma unroll
    for (int tt = 0; tt < 9; ++tt) {
        int w = tt * 16 + col;
        int wy = w / 12, wx = w % 12;
        int py = y0 + wy - 4, px = x0 + wx - 4;
        bool v = (py >= 0) && (py < H) && (px >= 0) && (px < W);
        b_off[tt] = v ? (((b * H + py) * W + px) * 32 + kg * 8) : (zoff + kg * 8);
        badv[tt] = v ? NP32_3 : 0;
        if (v) vmask |= (1u << tt);
    }

    f32x4 acc[9] = {};
    #pragma unroll
    for (int kb = 0; kb < 8; ++kb) {
        bf16x8 av = *reinterpret_cast<const bf16x8*>(f1n + a_off + kb * NP32_3);
        #pragma unroll
        for (int tt = 0; tt < 9; ++tt) {
            bf16x8 bv = *reinterpret_cast<const bf16x8*>(f2n + b_off[tt]);
            acc[tt] = __builtin_amdgcn_mfma_f32_16x16x32_bf16(av, bv, acc[tt], 0, 0, 0);
            b_off[tt] += badv[tt];
        }
    }

    float inv1[4], dts[4];
    #pragma unroll
    for (int r = 0; r < 4; ++r) {
        int m = kg * 4 + r;
        int iy = m >> 2, ix = m & 3;
        int pix = (b * H + y0 + iy) * W + x0 + ix;
        inv1[r] = invn1[pix];
        dts[r]  = dt[pix];
    }
    #pragma unroll
    for (int tt = 0; tt < 9; ++tt) {
        int w = tt * 16 + col;
        int wy = w / 12, wx = w % 12;
        int py = y0 + wy - 4, px = x0 + wx - 4;
        float i2 = ((vmask >> tt) & 1u) ? invn2[(b * H + py) * W + px] : 0.f;
        #pragma unroll
        for (int r = 0; r < 4; ++r) {
            int m = kg * 4 + r;
            int iy = m >> 2, ix = m & 3;
            int oy = iy + 8 - wy, ox = ix + 8 - wx;
            if (oy >= 0 && oy < 9 && ox >= 0 && ox < 9) {
                int o = oy * 9 + ox;
                out[((size_t)(b * 81 + o) * H + (y0 + iy)) * W + (x0 + ix)]
                    = acc[tt][r] * inv1[r] * i2 + dts[r];
            }
        }
    }
}

// =====================================================================
// depth: one thread owns an 8x8 L0 patch; dt for all 4 levels
// =====================================================================
__global__ __launch_bounds__(256) void depth_kernel(
    const float* __restrict__ d1, const float* __restrict__ d2,
    const float* __restrict__ dw,
    float* __restrict__ dt0, float* __restrict__ dt1,
    float* __restrict__ dt2, float* __restrict__ dt3)
{
    int rid = blockIdx.x * 256 + threadIdx.x;
    if (rid >= 4 * 16 * 24) return;
    int b = rid / 384, rr = rid % 384, ry = rr / 24, rx = rr % 24;
    const int H = 128, W = 192;
    float w0 = dw[0];
    size_t base0 = ((size_t)b * H + ry * 8) * W + rx * 8;

    float q1[4][4], q2[4][4];
    #pragma unroll
    for (int yy = 0; yy < 4; ++yy) {
        float4 a0 = *reinterpret_cast<const float4*>(d1 + base0 + (2 * yy) * W);
        float4 a1 = *reinterpret_cast<const float4*>(d1 + base0 + (2 * yy) * W + 4);
        float4 a2 = *reinterpret_cast<const float4*>(d1 + base0 + (2 * yy + 1) * W);
        float4 a3 = *reinterpret_cast<const float4*>(d1 + base0 + (2 * yy + 1) * W + 4);
        float4 b0 = *reinterpret_cast<const float4*>(d2 + base0 + (2 * yy) * W);
        float4 b1 = *reinterpret_cast<const float4*>(d2 + base0 + (2 * yy) * W + 4);
        float4 b2 = *reinterpret_cast<const float4*>(d2 + base0 + (2 * yy + 1) * W);
        float4 b3 = *reinterpret_cast<const float4*>(d2 + base0 + (2 * yy + 1) * W + 4);
        float ra[2][8] = {{a0.x,a0.y,a0.z,a0.w,a1.x,a1.y,a1.z,a1.w},
                          {a2.x,a2.y,a2.z,a2.w,a3.x,a3.y,a3.z,a3.w}};
        float rb[2][8] = {{b0.x,b0.y,b0.z,b0.w,b1.x,b1.y,b1.z,b1.w},
                          {b2.x,b2.y,b2.z,b2.w,b3.x,b3.y,b3.z,b3.w}};
        #pragma unroll
        for (int e = 0; e < 2; ++e) {
            float o[8];
            #pragma unroll
            for (int xx = 0; xx < 8; ++xx) o[xx] = w0 * expf(-fabsf(ra[e][xx] - rb[e][xx]));
            *reinterpret_cast<float4*>(dt0 + base0 + (2 * yy + e) * W)     = make_float4(o[0], o[1], o[2], o[3]);
            *reinterpret_cast<float4*>(dt0 + base0 + (2 * yy + e) * W + 4) = make_float4(o[4], o[5], o[6], o[7]);
        }
        #pragma unroll
        for (int xx = 0; xx < 4; ++xx) {
            q1[yy][xx] = 0.25f * (ra[0][2 * xx] + ra[0][2 * xx + 1] + ra[1][2 * xx] + ra[1][2 * xx + 1]);
            q2[yy][xx] = 0.25f * (rb[0][2 * xx] + rb[0][2 * xx + 1] + rb[1][2 * xx] + rb[1][2 * xx + 1]);
        }
    }
    #pragma unroll
    for (int yy = 0; yy < 4; ++yy)
        #pragma unroll
        for (int xx = 0; xx < 4; ++xx)
            dt1[((size_t)b * 64 + ry * 4 + yy) * 96 + rx * 4 + xx] = w0 * expf(-fabsf(q1[yy][xx] - q2[yy][xx]));

    float r1[2][2], r2m[2][2];
    #pragma unroll
    for (int y = 0; y < 2; ++y)
        #pragma unroll
        for (int x = 0; x < 2; ++x) {
            r1[y][x]  = 0.25f * (q1[2 * y][2 * x] + q1[2 * y][2 * x + 1] + q1[2 * y + 1][2 * x] + q1[2 * y + 1][2 * x + 1]);
            r2m[y][x] = 0.25f * (q2[2 * y][2 * x] + q2[2 * y][2 * x + 1] + q2[2 * y + 1][2 * x] + q2[2 * y + 1][2 * x + 1]);
            dt2[((size_t)b * 32 + ry * 2 + y) * 48 + rx * 2 + x] = w0 * expf(-fabsf(r1[y][x] - r2m[y][x]));
        }
    float s1 = 0.25f * (r1[0][0] + r1[0][1] + r1[1][0] + r1[1][1]);
    float s2 = 0.25f * (r2m[0][0] + r2m[0][1] + r2m[1][0] + r2m[1][1]);
    dt3[((size_t)b * 16 + ry) * 24 + rx] = w0 * expf(-fabsf(s1 - s2));
}

// =====================================================================
extern "C" void kernel_launch(void* const* d_in, const int* in_sizes, int n_in,
                              void* d_out, int out_size, void* d_ws, size_t ws_size,
                              hipStream_t stream) {
    const float* f1 = (const float*)d_in[0];
    const float* f2 = (const float*)d_in[1];
    const float* d1 = (const float*)d_in[2];
    const float* d2 = (const float*)d_in[3];
    const float* dw = (const float*)d_in[4];
    float* out = (float*)d_out;
    float* ws  = (float*)d_ws;

    // ---------------- float workspace carve ----------------
    size_t o = 0;
    float* in1_0 = ws + o; o += (size_t)4 * 128 * 192;
    float* in1_1 = ws + o; o += (size_t)4 * 64 * 96;
    float* in1_2 = ws + o; o += (size_t)4 * 32 * 48;
    float* in1_3 = ws + o; o += (size_t)4 * 16 * 24;
    float* in2_0 = ws + o; o += (size_t)4 * 128 * 192;
    float* in2_1 = ws + o; o += (size_t)4 * 64 * 96;
    float* in2_2 = ws + o; o += (size_t)4 * 32 * 48;
    float* in2_3 = ws + o; o += (size_t)4 * 16 * 24;
    float* dt_0 = ws + o; o += (size_t)4 * 128 * 192;
    float* dt_1 = ws + o; o += (size_t)4 * 64 * 96;
    float* dt_2 = ws + o; o += (size_t)4 * 32 * 48;
    float* dt_3 = ws + o; o += (size_t)4 * 16 * 24;
    o = (o + 7) & ~(size_t)7;

    // ---------------- bf16 (ushort) workspace carve ----------------
    ushort_t* sws = (ushort_t*)(ws + o);
    const size_t L0 = (size_t)4 * 128 * 192 * 256;
    const size_t L1 = (size_t)4 * 64 * 96 * 256;
    const size_t L2 = (size_t)4 * 32 * 48 * 256;
    const size_t L3 = (size_t)4 * 16 * 24 * 256;
    const size_t FT = L0 + L1 + L2 + L3;
    ushort_t* f1n0 = sws;
    ushort_t* f1n1 = f1n0 + L0;
    ushort_t* f1n2 = f1n1 + L1;
    ushort_t* f1n3 = f1n2 + L2;
    ushort_t* f2n0 = sws + FT;
    ushort_t* f2n1 = f2n0 + L0;
    ushort_t* f2n2 = f2n1 + L1;
    ushort_t* f2n3 = f2n2 + L2;
    ushort_t* zblk = sws + 2 * FT;
    size_t need = o * 4 + (2 * FT + 256) * 2;
    if (ws_size < need) return;   // proven sufficient in prior rounds

    hipMemsetAsync(zblk, 0, 512, stream);

    depth_kernel<<<dim3(6), 256, 0, stream>>>(d1, d2, dw, dt_0, dt_1, dt_2, dt_3);

    PrepPtrs Pa = { f1n0, f1n1, f1n2, f1n3, in1_0, in1_1, in1_2, in1_3 };
    PrepPtrs Pb = { f2n0, f2n1, f2n2, f2n3, in2_0, in2_1, in2_2, in2_3 };
    pyr_prep_kernel<<<dim3(384, 2), 256, 0, stream>>>(f1, f2, Pa, Pb);

    CorrLvl lv0 = { f1n0, f2n0, in1_0, in2_0, dt_0, out,           128, 192, 12, 16, NP32_0 };
    CorrLvl lv1 = { f1n1, f2n1, in1_1, in2_1, dt_1, out + 7962624,  64,  96,  6,  8, NP32_1 };
    CorrLvl lv2 = { f1n2, f2n2, in1_2, in2_2, dt_2, out + 9953280,  32,  48,  3,  4, NP32_2 };
    corr_fused_kernel<<<dim3(1008), 256, 0, stream>>>(lv0, lv1, lv2, zblk);

    corr_mfma_kernel<<<dim3(96 / 4), 256, 0, stream>>>(f1n3, f2n3, in1_3, in2_3, dt_3, out + 10450944, 16, 24, 6, 4,
                                                       (int)(2 * FT - (size_t)(f2n3 - sws)));
}

// Round 11
// 240.450 us; speedup vs baseline: 1.3196x; 1.0032x over previous
//
#include <hip/hip_runtime.h>
#include <hip/hip_bf16.h>

typedef __attribute__((ext_vector_type(8))) __bf16 bf16x8;
typedef __attribute__((ext_vector_type(4))) float f32x4;
typedef unsigned short ushort_t;
typedef unsigned int uint_t;

#define CCH 256
#define BB 4

// kc-plane strides in shorts: level npix * 32 ch
#define NP32_0 3145728   // 4*128*192*32
#define NP32_1 786432    // 4*64*96*32
#define NP32_2 196608    // 4*32*48*32
#define NP32_3 49152     // 4*16*24*32

#define NPX0 98304
#define NPX1 24576
#define NPX2 6144
#define NPX3 1536
#define NPXT (NPX0 + NPX1 + NPX2 + NPX3)   // 130560

__device__ __forceinline__ ushort_t f2b(float v) {
    __hip_bfloat16 h = __float2bfloat16(v);
    return *reinterpret_cast<ushort_t*>(&h);
}

__device__ __forceinline__ void gload16(const void* g, void* l) {
    __builtin_amdgcn_global_load_lds(
        (const __attribute__((address_space(1))) void*)g,
        (__attribute__((address_space(3))) void*)l, 16, 0, 0);
}

struct PrepOut {
    ushort_t* o0; ushort_t* o1; ushort_t* o2; ushort_t* o3;
    float* s0; float* s1; float* s2; float* s3;     // partial ssq [8][npx]
    float* n0; float* n1; float* n2; float* n3;     // invnorms
};

// =====================================================================
// prep_stream: barrier-free, LDS-free pyramid prep.
// 1 wave/block; thread owns a 2x2 L0 patch; block = 16x16 px x 32 ch
// (one kc chunk). Pooling via in-register + __shfl_xor (all in-wave).
// ssq -> per-kc partial arrays (summed by invnorm_fin_kernel).
// =====================================================================
__global__ __launch_bounds__(64) void prep_stream_kernel(
    const float* __restrict__ fa, const float* __restrict__ fb,
    PrepOut Pa, PrepOut Pb)
{
    const int H = 128, W = 192, HW = H * W;
    const float* fin = blockIdx.y ? fb : fa;
    PrepOut P = blockIdx.y ? Pb : Pa;

    int bid = blockIdx.x;
    int kc = bid & 7;
    int r0i = bid >> 3;
    int xc = r0i % 12;
    int ys = (r0i / 12) % 8;
    int b  = r0i / 96;

    int t = threadIdx.x;
    int ty = t >> 3, tx = t & 7;
    int row0 = ys * 16 + 2 * ty;
    int col0 = xc * 16 + 2 * tx;

    const float* base = fin + (size_t)(b * 256 + kc * 32) * HW + (size_t)row0 * W + col0;

    uint_t uu0[4][16];
    uint_t uu1[16], uu2[16], uu3[16];
    float sq0 = 0.f, sq1v = 0.f, sq2v = 0.f, sq3v = 0.f;
    float ssqA = 0.f, ssqB = 0.f, ssqC = 0.f, ssqD = 0.f;
    float ssq1 = 0.f, ssq2 = 0.f, ssq3 = 0.f;
    (void)sq0; (void)sq1v; (void)sq2v; (void)sq3v;

    bool own2 = ((tx & 1) | (ty & 1)) == 0;
    bool own3 = ((tx & 3) | (ty & 3)) == 0;

    #pragma unroll
    for (int cc = 0; cc < 32; ++cc) {
        float2 ra = *reinterpret_cast<const float2*>(base + (size_t)cc * HW);
        float2 rb = *reinterpret_cast<const float2*>(base + (size_t)cc * HW + W);

        ssqA = fmaf(ra.x, ra.x, ssqA);
        ssqB = fmaf(ra.y, ra.y, ssqB);
        ssqC = fmaf(rb.x, rb.x, ssqC);
        ssqD = fmaf(rb.y, rb.y, ssqD);

        ushort_t b00 = f2b(ra.x), b01 = f2b(ra.y), b10 = f2b(rb.x), b11 = f2b(rb.y);
        if ((cc & 1) == 0) {
            uu0[0][cc >> 1] = (uint_t)b00;
            uu0[1][cc >> 1] = (uint_t)b01;
            uu0[2][cc >> 1] = (uint_t)b10;
            uu0[3][cc >> 1] = (uint_t)b11;
        } else {
            uu0[0][cc >> 1] |= ((uint_t)b00) << 16;
            uu0[1][cc >> 1] |= ((uint_t)b01) << 16;
            uu0[2][cc >> 1] |= ((uint_t)b10) << 16;
            uu0[3][cc >> 1] |= ((uint_t)b11) << 16;
        }

        float l1 = 0.25f * (ra.x + ra.y + rb.x + rb.y);
        ssq1 = fmaf(l1, l1, ssq1);
        if ((cc & 1) == 0) uu1[cc >> 1] = (uint_t)f2b(l1);
        else               uu1[cc >> 1] |= ((uint_t)f2b(l1)) << 16;

        float sa = l1 + __shfl_xor(l1, 1);
        float l2 = 0.25f * (sa + __shfl_xor(sa, 8));
        float sb = l2 + __shfl_xor(l2, 2);
        float l3 = 0.25f * (sb + __shfl_xor(sb, 16));

        if (own2) ssq2 = fmaf(l2, l2, ssq2);
        if (own3) ssq3 = fmaf(l3, l3, ssq3);
        if ((cc & 1) == 0) { uu2[cc >> 1] = (uint_t)f2b(l2); uu3[cc >> 1] = (uint_t)f2b(l3); }
        else               { uu2[cc >> 1] |= ((uint_t)f2b(l2)) << 16; uu3[cc >> 1] |= ((uint_t)f2b(l3)) << 16; }
    }

    // ---- L0 stores: 4 pixels x 64B ----
    float sqv[4] = { ssqA, ssqB, ssqC, ssqD };
    #pragma unroll
    for (int r = 0; r < 2; ++r)
        #pragma unroll
        for (int cx = 0; cx < 2; ++cx) {
            int pxi = r * 2 + cx;
            size_t px = (size_t)(b * H + row0 + r) * W + col0 + cx;
            ushort_t* dst = P.o0 + (size_t)kc * NP32_0 + px * 32;
            *reinterpret_cast<uint4*>(dst +  0) = make_uint4(uu0[pxi][0],  uu0[pxi][1],  uu0[pxi][2],  uu0[pxi][3]);
            *reinterpret_cast<uint4*>(dst +  8) = make_uint4(uu0[pxi][4],  uu0[pxi][5],  uu0[pxi][6],  uu0[pxi][7]);
            *reinterpret_cast<uint4*>(dst + 16) = make_uint4(uu0[pxi][8],  uu0[pxi][9],  uu0[pxi][10], uu0[pxi][11]);
            *reinterpret_cast<uint4*>(dst + 24) = make_uint4(uu0[pxi][12], uu0[pxi][13], uu0[pxi][14], uu0[pxi][15]);
            P.s0[(size_t)kc * NPX0 + px] = sqv[pxi];
        }

    // ---- L1 store ----
    size_t l1px = (size_t)(b * 64 + ys * 8 + ty) * 96 + xc * 8 + tx;
    {
        ushort_t* dst = P.o1 + (size_t)kc * NP32_1 + l1px * 32;
        *reinterpret_cast<uint4*>(dst +  0) = make_uint4(uu1[0],  uu1[1],  uu1[2],  uu1[3]);
        *reinterpret_cast<uint4*>(dst +  8) = make_uint4(uu1[4],  uu1[5],  uu1[6],  uu1[7]);
        *reinterpret_cast<uint4*>(dst + 16) = make_uint4(uu1[8],  uu1[9],  uu1[10], uu1[11]);
        *reinterpret_cast<uint4*>(dst + 24) = make_uint4(uu1[12], uu1[13], uu1[14], uu1[15]);
        P.s1[(size_t)kc * NPX1 + l1px] = ssq1;
    }

    // ---- L2 store (owner lanes) ----
    if (own2) {
        size_t l2px = (size_t)(b * 32 + ys * 4 + (ty >> 1)) * 48 + xc * 4 + (tx >> 1);
        ushort_t* dst = P.o2 + (size_t)kc * NP32_2 + l2px * 32;
        *reinterpret_cast<uint4*>(dst +  0) = make_uint4(uu2[0],  uu2[1],  uu2[2],  uu2[3]);
        *reinterpret_cast<uint4*>(dst +  8) = make_uint4(uu2[4],  uu2[5],  uu2[6],  uu2[7]);
        *reinterpret_cast<uint4*>(dst + 16) = make_uint4(uu2[8],  uu2[9],  uu2[10], uu2[11]);
        *reinterpret_cast<uint4*>(dst + 24) = make_uint4(uu2[12], uu2[13], uu2[14], uu2[15]);
        P.s2[(size_t)kc * NPX2 + l2px] = ssq2;
    }

    // ---- L3 store (owner lanes) ----
    if (own3) {
        size_t l3px = (size_t)(b * 16 + ys * 2 + (ty >> 2)) * 24 + xc * 2 + (tx >> 2);
        ushort_t* dst = P.o3 + (size_t)kc * NP32_3 + l3px * 32;
        *reinterpret_cast<uint4*>(dst +  0) = make_uint4(uu3[0],  uu3[1],  uu3[2],  uu3[3]);
        *reinterpret_cast<uint4*>(dst +  8) = make_uint4(uu3[4],  uu3[5],  uu3[6],  uu3[7]);
        *reinterpret_cast<uint4*>(dst + 16) = make_uint4(uu3[8],  uu3[9],  uu3[10], uu3[11]);
        *reinterpret_cast<uint4*>(dst + 24) = make_uint4(uu3[12], uu3[13], uu3[14], uu3[15]);
        P.s3[(size_t)kc * NPX3 + l3px] = ssq3;
    }
}

// =====================================================================
// invnorm finalize: sum the 8 kc-partials, write 1/max(sqrt,eps)
// =====================================================================
__global__ __launch_bounds__(256) void invnorm_fin_kernel(PrepOut Pa, PrepOut Pb)
{
    int tid = blockIdx.x * 256 + threadIdx.x;
    if (tid >= 2 * NPXT) return;
    PrepOut P = (tid >= NPXT) ? Pb : Pa;
    int i = (tid >= NPXT) ? (tid - NPXT) : tid;

    const float* s; float* n; int npx, j;
    if (i < NPX0)                       { s = P.s0; n = P.n0; npx = NPX0; j = i; }
    else if (i < NPX0 + NPX1)           { s = P.s1; n = P.n1; npx = NPX1; j = i - NPX0; }
    else if (i < NPX0 + NPX1 + NPX2)    { s = P.s2; n = P.n2; npx = NPX2; j = i - NPX0 - NPX1; }
    else                                { s = P.s3; n = P.n3; npx = NPX3; j = i - NPX0 - NPX1 - NPX2; }

    float sum = 0.f;
    #pragma unroll
    for (int k = 0; k < 8; ++k) sum += s[(size_t)k * npx + j];
    n[j] = 1.f / fmaxf(sqrtf(sum), 1e-12f);
}

// =====================================================================
// corr_fused (unchanged from round 10 — proven)
// =====================================================================
struct CorrLvl {
    const ushort_t* f1n; const ushort_t* f2n;
    const float* in1; const float* in2; const float* dt;
    float* out;
    int H, W, TX, TY, npix32;
};

__global__ __launch_bounds__(256, 2) void corr_fused_kernel(
    CorrLvl Lv0, CorrLvl Lv1, CorrLvl Lv2, const ushort_t* __restrict__ zblk)
{
    __shared__ char smem[65536];
    char* As = smem;
    char* Bs = smem + 16384;

    int bid = blockIdx.x;
    CorrLvl L;
    int local;
    if (bid < 768)      { L = Lv0; local = bid; }
    else if (bid < 960) { L = Lv1; local = bid - 768; }
    else                { L = Lv2; local = bid - 960; }

    int H = L.H, W = L.W, TX = L.TX, TY = L.TY, npix32 = L.npix32;
    int cpx = (BB * TX * TY) >> 3;
    int swz = (local & 7) * cpx + (local >> 3);
    int tx = swz % TX;
    int ty = (swz / TX) % TY;
    int b  = swz / (TX * TY);
    int x0 = tx * 16, y0 = ty * 8;

    int tid = threadIdx.x;
    int w = tid >> 6, lane = tid & 63;
    int kg = lane >> 4, col = lane & 15;
    int r2 = col >> 2, c2 = col & 3;
    int sy = w >> 1, p = w & 1;
    int kgx = kg ^ c2;

    const ushort_t* srcA[2]; char* ldsA[2];
    #pragma unroll
    for (int q = 0; q < 2; ++q) {
        int row = w * 2 + q;
        int px = lane >> 2, js = lane & 3;
        int j = js ^ (px & 3);
        srcA[q] = L.f1n + ((size_t)((b * H + y0 + row) * W) + x0 + px) * 32 + j * 8;
        ldsA[q] = As + row * 1024;
    }
    const ushort_t* srcB[6]; int advB[6]; char* ldsB[6];
    #pragma unroll
    for (int q = 0; q < 6; ++q) {
        int u = (w * 6 + q) * 64 + lane;
        int row = u / 96, rem = u % 96;
        int px = rem >> 2, js = rem & 3;
        int j = js ^ (px & 3);
        int py = y0 - 4 + row, pxg = x0 - 4 + px;
        bool v = (py >= 0) && (py < H) && (pxg >= 0) && (pxg < W);
        srcB[q] = v ? (L.f2n + ((size_t)((b * H + py) * W) + pxg) * 32 + j * 8) : (zblk + j * 8);
        advB[q] = v ? npix32 : 0;
        ldsB[q] = Bs + (w * 6 + q) * 1024;
    }

    int aoff[2], boff[3][4];
    #pragma unroll
    for (int s = 0; s < 2; ++s) {
        int ly = 4 * sy + r2;
        int lx = 4 * (2 * p + s) + c2;
        aoff[s] = ((ly * 16 + lx) * 4 + kgx) * 16;
    }
    #pragma unroll
    for (int i = 0; i < 3; ++i)
        #pragma unroll
        for (int j = 0; j < 4; ++j) {
            int wy = 4 * (sy + i) + r2;
            int wx = 4 * (2 * p + j) + c2;
            boff[i][j] = ((wy * 24 + wx) * 4 + kgx) * 16;
        }

    f32x4 acc0[3][3] = {};
    f32x4 acc1[3][3] = {};

    #pragma unroll
    for (int q = 0; q < 2; ++q) { gload16(srcA[q], ldsA[q]); srcA[q] += npix32; }
    #pragma unroll
    for (int q = 0; q < 6; ++q) { gload16(srcB[q], ldsB[q]); srcB[q] += advB[q]; }

    int buf = 0;
    #pragma unroll 1
    for (int kc = 0; kc < 8; ++kc) {
        if (kc < 7) {
            int boA = (buf ^ 1) * 8192;
            int boB = (buf ^ 1) * 24576;
            #pragma unroll
            for (int q = 0; q < 2; ++q) { gload16(srcA[q], ldsA[q] + boA); srcA[q] += npix32; }
            #pragma unroll
            for (int q = 0; q < 6; ++q) { gload16(srcB[q], ldsB[q] + boB); srcB[q] += advB[q]; }
            __builtin_amdgcn_sched_barrier(0);
            asm volatile("s_waitcnt vmcnt(8)" ::: "memory");
        } else {
            __builtin_amdgcn_sched_barrier(0);
            asm volatile("s_waitcnt vmcnt(0)" ::: "memory");
        }
        __builtin_amdgcn_s_barrier();
        __builtin_amdgcn_sched_barrier(0);

        const char* Ab = As + buf * 8192;
        const char* Bb = Bs + buf * 24576;
        bf16x8 av0 = *(const bf16x8*)(Ab + aoff[0]);
        bf16x8 av1 = *(const bf16x8*)(Ab + aoff[1]);
        #pragma unroll
        for (int i = 0; i < 3; ++i) {
            #pragma unroll
            for (int j = 0; j < 4; ++j) {
                bf16x8 bv = *(const bf16x8*)(Bb + boff[i][j]);
                if (j < 3) acc0[i][j]     = __builtin_amdgcn_mfma_f32_16x16x32_bf16(av0, bv, acc0[i][j], 0, 0, 0);
                if (j > 0) acc1[i][j - 1] = __builtin_amdgcn_mfma_f32_16x16x32_bf16(av1, bv, acc1[i][j - 1], 0, 0, 0);
            }
        }
        if (kc < 7) {
            __builtin_amdgcn_sched_barrier(0);
            __builtin_amdgcn_s_barrier();
            __builtin_amdgcn_sched_barrier(0);
        }
        buf ^= 1;
    }

    float inv1v[2][4], dtv[2][4];
    #pragma unroll
    for (int s = 0; s < 2; ++s) {
        int sxs = 2 * p + s;
        #pragma unroll
        for (int rr = 0; rr < 4; ++rr) {
            int m = kg * 4 + rr;
            int iy = m >> 2, ix = m & 3;
            int pix = (b * H + y0 + 4 * sy + iy) * W + x0 + 4 * sxs + ix;
            inv1v[s][rr] = L.in1[pix];
            dtv[s][rr]   = L.dt[pix];
        }
    }
    #pragma unroll
    for (int s = 0; s < 2; ++s) {
        int sxs = 2 * p + s;
        #pragma unroll
        for (int i = 0; i < 3; ++i) {
            #pragma unroll
            for (int jj = 0; jj < 3; ++jj) {
                int wy = 4 * (sy + i) + r2;
                int wxr = 4 * (sxs + jj) + c2;
                int py = y0 - 4 + wy, px = x0 - 4 + wxr;
                bool v = (py >= 0) && (py < H) && (px >= 0) && (px < W);
                float i2 = v ? L.in2[(b * H + py) * W + px] : 0.f;
                f32x4 a = (s == 0) ? acc0[i][jj] : acc1[i][jj];
                #pragma unroll
                for (int rr = 0; rr < 4; ++rr) {
                    int m = kg * 4 + rr;
                    int iy = m >> 2, ix = m & 3;
                    int oy = iy + 8 - (4 * i + r2);
                    int ox = ix + 8 - (4 * jj + c2);
                    if (oy >= 0 && oy < 9 && ox >= 0 && ox < 9) {
                        int gy = y0 + 4 * sy + iy, gx = x0 + 4 * sxs + ix;
                        L.out[((size_t)(b * 81 + oy * 9 + ox) * H + gy) * W + gx]
                            = a[rr] * inv1v[s][rr] * i2 + dtv[s][rr];
                    }
                }
            }
        }
    }
}

// =====================================================================
// corr_mfma — L3 only (unchanged)
// =====================================================================
__global__ __launch_bounds__(256) void corr_mfma_kernel(
    const ushort_t* __restrict__ f1n, const ushort_t* __restrict__ f2n,
    const float* __restrict__ invn1, const float* __restrict__ invn2,
    const float* __restrict__ dt, float* __restrict__ out,
    int H, int W, int TX, int TY, int zoff)
{
    int wid  = threadIdx.x >> 6;
    int lane = threadIdx.x & 63;
    int tile = blockIdx.x * 4 + wid;
    int ntiles = BB * TY * TX;
    if (tile >= ntiles) return;
    int tx = tile % TX;
    int ty = (tile / TX) % TY;
    int b  = tile / (TX * TY);
    int x0 = tx * 4, y0 = ty * 4;

    int col = lane & 15;
    int kg  = lane >> 4;

    int iyA = col >> 2, ixA = col & 3;
    int a_off = (((b * H + y0 + iyA) * W) + x0 + ixA) * 32 + kg * 8;

    int b_off[9], badv[9];
    uint_t vmask = 0;
    #pragma unroll
    for (int tt = 0; tt < 9; ++tt) {
        int w = tt * 16 + col;
        int wy = w / 12, wx = w % 12;
        int py = y0 + wy - 4, px = x0 + wx - 4;
        bool v = (py >= 0) && (py < H) && (px >= 0) && (px < W);
        b_off[tt] = v ? (((b * H + py) * W + px) * 32 + kg * 8) : (zoff + kg * 8);
        badv[tt] = v ? NP32_3 : 0;
        if (v) vmask |= (1u << tt);
    }

    f32x4 acc[9] = {};
    #pragma unroll
    for (int kb = 0; kb < 8; ++kb) {
        bf16x8 av = *reinterpret_cast<const bf16x8*>(f1n + a_off + kb * NP32_3);
        #pragma unroll
        for (int tt = 0; tt < 9; ++tt) {
            bf16x8 bv = *reinterpret_cast<const bf16x8*>(f2n + b_off[tt]);
            acc[tt] = __builtin_amdgcn_mfma_f32_16x16x32_bf16(av, bv, acc[tt], 0, 0, 0);
            b_off[tt] += badv[tt];
        }
    }

    float inv1[4], dts[4];
    #pragma unroll
    for (int r = 0; r < 4; ++r) {
        int m = kg * 4 + r;
        int iy = m >> 2, ix = m & 3;
        int pix = (b * H + y0 + iy) * W + x0 + ix;
        inv1[r] = invn1[pix];
        dts[r]  = dt[pix];
    }
    #pragma unroll
    for (int tt = 0; tt < 9; ++tt) {
        int w = tt * 16 + col;
        int wy = w / 12, wx = w % 12;
        int py = y0 + wy - 4, px = x0 + wx - 4;
        float i2 = ((vmask >> tt) & 1u) ? invn2[(b * H + py) * W + px] : 0.f;
        #pragma unroll
        for (int r = 0; r < 4; ++r) {
            int m = kg * 4 + r;
            int iy = m >> 2, ix = m & 3;
            int oy = iy + 8 - wy, ox = ix + 8 - wx;
            if (oy >= 0 && oy < 9 && ox >= 0 && ox < 9) {
                int o = oy * 9 + ox;
                out[((size_t)(b * 81 + o) * H + (y0 + iy)) * W + (x0 + ix)]
                    = acc[tt][r] * inv1[r] * i2 + dts[r];
            }
        }
    }
}

// =====================================================================
// depth (unchanged)
// =====================================================================
__global__ __launch_bounds__(256) void depth_kernel(
    const float* __restrict__ d1, const float* __restrict__ d2,
    const float* __restrict__ dw,
    float* __restrict__ dt0, float* __restrict__ dt1,
    float* __restrict__ dt2, float* __restrict__ dt3)
{
    int rid = blockIdx.x * 256 + threadIdx.x;
    if (rid >= 4 * 16 * 24) return;
    int b = rid / 384, rr = rid % 384, ry = rr / 24, rx = rr % 24;
    const int H = 128, W = 192;
    float w0 = dw[0];
    size_t base0 = ((size_t)b * H + ry * 8) * W + rx * 8;

    float q1[4][4], q2[4][4];
    #pragma unroll
    for (int yy = 0; yy < 4; ++yy) {
        float4 a0 = *reinterpret_cast<const float4*>(d1 + base0 + (2 * yy) * W);
        float4 a1 = *reinterpret_cast<const float4*>(d1 + base0 + (2 * yy) * W + 4);
        float4 a2 = *reinterpret_cast<const float4*>(d1 + base0 + (2 * yy + 1) * W);
        float4 a3 = *reinterpret_cast<const float4*>(d1 + base0 + (2 * yy + 1) * W + 4);
        float4 b0 = *reinterpret_cast<const float4*>(d2 + base0 + (2 * yy) * W);
        float4 b1 = *reinterpret_cast<const float4*>(d2 + base0 + (2 * yy) * W + 4);
        float4 b2 = *reinterpret_cast<const float4*>(d2 + base0 + (2 * yy + 1) * W);
        float4 b3 = *reinterpret_cast<const float4*>(d2 + base0 + (2 * yy + 1) * W + 4);
        float ra[2][8] = {{a0.x,a0.y,a0.z,a0.w,a1.x,a1.y,a1.z,a1.w},
                          {a2.x,a2.y,a2.z,a2.w,a3.x,a3.y,a3.z,a3.w}};
        float rb[2][8] = {{b0.x,b0.y,b0.z,b0.w,b1.x,b1.y,b1.z,b1.w},
                          {b2.x,b2.y,b2.z,b2.w,b3.x,b3.y,b3.z,b3.w}};
        #pragma unroll
        for (int e = 0; e < 2; ++e) {
            float o[8];
            #pragma unroll
            for (int xx = 0; xx < 8; ++xx) o[xx] = w0 * expf(-fabsf(ra[e][xx] - rb[e][xx]));
            *reinterpret_cast<float4*>(dt0 + base0 + (2 * yy + e) * W)     = make_float4(o[0], o[1], o[2], o[3]);
            *reinterpret_cast<float4*>(dt0 + base0 + (2 * yy + e) * W + 4) = make_float4(o[4], o[5], o[6], o[7]);
        }
        #pragma unroll
        for (int xx = 0; xx < 4; ++xx) {
            q1[yy][xx] = 0.25f * (ra[0][2 * xx] + ra[0][2 * xx + 1] + ra[1][2 * xx] + ra[1][2 * xx + 1]);
            q2[yy][xx] = 0.25f * (rb[0][2 * xx] + rb[0][2 * xx + 1] + rb[1][2 * xx] + rb[1][2 * xx + 1]);
        }
    }
    #pragma unroll
    for (int yy = 0; yy < 4; ++yy)
        #pragma unroll
        for (int xx = 0; xx < 4; ++xx)
            dt1[((size_t)b * 64 + ry * 4 + yy) * 96 + rx * 4 + xx] = w0 * expf(-fabsf(q1[yy][xx] - q2[yy][xx]));

    float r1[2][2], r2m[2][2];
    #pragma unroll
    for (int y = 0; y < 2; ++y)
        #pragma unroll
        for (int x = 0; x < 2; ++x) {
            r1[y][x]  = 0.25f * (q1[2 * y][2 * x] + q1[2 * y][2 * x + 1] + q1[2 * y + 1][2 * x] + q1[2 * y + 1][2 * x + 1]);
            r2m[y][x] = 0.25f * (q2[2 * y][2 * x] + q2[2 * y][2 * x + 1] + q2[2 * y + 1][2 * x] + q2[2 * y + 1][2 * x + 1]);
            dt2[((size_t)b * 32 + ry * 2 + y) * 48 + rx * 2 + x] = w0 * expf(-fabsf(r1[y][x] - r2m[y][x]));
        }
    float s1 = 0.25f * (r1[0][0] + r1[0][1] + r1[1][0] + r1[1][1]);
    float s2 = 0.25f * (r2m[0][0] + r2m[0][1] + r2m[1][0] + r2m[1][1]);
    dt3[((size_t)b * 16 + ry) * 24 + rx] = w0 * expf(-fabsf(s1 - s2));
}

// =====================================================================
extern "C" void kernel_launch(void* const* d_in, const int* in_sizes, int n_in,
                              void* d_out, int out_size, void* d_ws, size_t ws_size,
                              hipStream_t stream) {
    const float* f1 = (const float*)d_in[0];
    const float* f2 = (const float*)d_in[1];
    const float* d1 = (const float*)d_in[2];
    const float* d2 = (const float*)d_in[3];
    const float* dw = (const float*)d_in[4];
    float* out = (float*)d_out;
    float* ws  = (float*)d_ws;

    // ---------------- float workspace carve ----------------
    size_t o = 0;
    float* in1_0 = ws + o; o += NPX0;
    float* in1_1 = ws + o; o += NPX1;
    float* in1_2 = ws + o; o += NPX2;
    float* in1_3 = ws + o; o += NPX3;
    float* in2_0 = ws + o; o += NPX0;
    float* in2_1 = ws + o; o += NPX1;
    float* in2_2 = ws + o; o += NPX2;
    float* in2_3 = ws + o; o += NPX3;
    float* dt_0 = ws + o; o += NPX0;
    float* dt_1 = ws + o; o += NPX1;
    float* dt_2 = ws + o; o += NPX2;
    float* dt_3 = ws + o; o += NPX3;
    // partial ssq arrays [8][npx] per level per tensor
    float* s1_0 = ws + o; o += (size_t)8 * NPX0;
    float* s1_1 = ws + o; o += (size_t)8 * NPX1;
    float* s1_2 = ws + o; o += (size_t)8 * NPX2;
    float* s1_3 = ws + o; o += (size_t)8 * NPX3;
    float* s2_0 = ws + o; o += (size_t)8 * NPX0;
    float* s2_1 = ws + o; o += (size_t)8 * NPX1;
    float* s2_2 = ws + o; o += (size_t)8 * NPX2;
    float* s2_3 = ws + o; o += (size_t)8 * NPX3;
    o = (o + 7) & ~(size_t)7;

    // ---------------- bf16 (ushort) workspace carve ----------------
    ushort_t* sws = (ushort_t*)(ws + o);
    const size_t L0 = (size_t)NPX0 * 256;
    const size_t L1 = (size_t)NPX1 * 256;
    const size_t L2 = (size_t)NPX2 * 256;
    const size_t L3 = (size_t)NPX3 * 256;
    const size_t FT = L0 + L1 + L2 + L3;
    ushort_t* f1n0 = sws;
    ushort_t* f1n1 = f1n0 + L0;
    ushort_t* f1n2 = f1n1 + L1;
    ushort_t* f1n3 = f1n2 + L2;
    ushort_t* f2n0 = sws + FT;
    ushort_t* f2n1 = f2n0 + L0;
    ushort_t* f2n2 = f2n1 + L1;
    ushort_t* f2n3 = f2n2 + L2;
    ushort_t* zblk = sws + 2 * FT;
    size_t need = o * 4 + (2 * FT + 256) * 2;
    if (ws_size < need) return;

    hipMemsetAsync(zblk, 0, 512, stream);

    depth_kernel<<<dim3(6), 256, 0, stream>>>(d1, d2, dw, dt_0, dt_1, dt_2, dt_3);

    PrepOut Pa = { f1n0, f1n1, f1n2, f1n3, s1_0, s1_1, s1_2, s1_3, in1_0, in1_1, in1_2, in1_3 };
    PrepOut Pb = { f2n0, f2n1, f2n2, f2n3, s2_0, s2_1, s2_2, s2_3, in2_0, in2_1, in2_2, in2_3 };

    // barrier-free streaming prep: 3072 one-wave blocks per tensor
    prep_stream_kernel<<<dim3(3072, 2), 64, 0, stream>>>(f1, f2, Pa, Pb);
    invnorm_fin_kernel<<<dim3((2 * NPXT + 255) / 256), 256, 0, stream>>>(Pa, Pb);

    CorrLvl lv0 = { f1n0, f2n0, in1_0, in2_0, dt_0, out,           128, 192, 12, 16, NP32_0 };
    CorrLvl lv1 = { f1n1, f2n1, in1_1, in2_1, dt_1, out + 7962624,  64,  96,  6,  8, NP32_1 };
    CorrLvl lv2 = { f1n2, f2n2, in1_2, in2_2, dt_2, out + 9953280,  32,  48,  3,  4, NP32_2 };
    corr_fused_kernel<<<dim3(1008), 256, 0, stream>>>(lv0, lv1, lv2, zblk);

    corr_mfma_kernel<<<dim3(96 / 4), 256, 0, stream>>>(f1n3, f2n3, in1_3, in2_3, dt_3, out + 10450944, 16, 24, 6, 4,
                                                       (int)(2 * FT - (size_t)(f2n3 - sws)));
}